// Round 11
// baseline (1114.160 us; speedup 1.0000x reference)
//
#include <hip/hip_runtime.h>
#include <hip/hip_bf16.h>
#include <cstdint>
#include <math.h>

// ---------------------------------------------------------------------------
// AdaptiveMCTSReasoner  B=16, S=1024, H=1024, MAX_SIMS=100, K_FOCUS=3
// Round 11: pipelined GEMM (T3/T4 minimum 2-phase): double-buffered LDS,
// ONE barrier per K-step, next-tile gll issued before compute so the
// vmcnt(0)-at-barrier drain hides under MFMA+ds_read. Policy folded into the
// same kernel as a K=3072 GEMM ([Ahi|Ahi|Alo]·[Whi;Wlo;Whi]) with fused
// focus-logit epilogue. Workspace aliased (WT3 in NS, root_lo=acc_bf) to
// 123.6MB < round-10's proven 127.8MB floor. Selection path byte-identical.
// ---------------------------------------------------------------------------

#define SEQ 1024
#define BATCH 16
#define HDIM 1024
#define NSIM 100
#define NCHAIN (NSIM * BATCH)   // 1600
#define SHC (SEQ * HDIM)

typedef short bf16x8 __attribute__((ext_vector_type(8)));
typedef float f32x4 __attribute__((ext_vector_type(4)));
typedef float float4v __attribute__((ext_vector_type(4)));

__device__ __forceinline__ unsigned short f2bf(float f) {
    union { float f; uint32_t u; } c; c.f = f;
    uint32_t u = c.u;
    return (unsigned short)((u + 0x7FFFu + ((u >> 16) & 1u)) >> 16);   // RNE
}
__device__ __forceinline__ float bf2f(unsigned short h) {
    union { uint32_t u; float f; } c; c.u = ((uint32_t)h) << 16;
    return c.f;
}

__device__ __forceinline__ void gll16(const void* g, void* l) {
    __builtin_amdgcn_global_load_lds(
        (const __attribute__((address_space(1))) void*)g,
        (__attribute__((address_space(3))) void*)l, 16, 0, 0);
}

__device__ __forceinline__ float gelu32(float x) {
    return 0.5f * x * (1.0f + erff(x * 0.70710678f));
}

// XCD-aware bijective swizzle (requires nwg % 8 == 0; all our grids qualify)
__device__ __forceinline__ void swz_block(int& bx, int& by) {
    int gx = gridDim.x;
    int h = blockIdx.y * gx + blockIdx.x;
    int nwg = gx * gridDim.y;
    int l = (h & 7) * (nwg >> 3) + (h >> 3);
    bx = l % gx; by = l / gx;
}

// ------------------------------- threefry ----------------------------------
__device__ __forceinline__ uint32_t rotl32(uint32_t v, int r) {
    return (v << r) | (v >> (32 - r));
}

__device__ __forceinline__ void threefry(uint32_t k0, uint32_t k1,
                                         uint32_t c0, uint32_t c1,
                                         uint32_t& o0, uint32_t& o1) {
    uint32_t ks0 = k0, ks1 = k1, ks2 = k0 ^ k1 ^ 0x1BD11BDAu;
    uint32_t x0 = c0 + ks0, x1 = c1 + ks1;
#define TFR(r) { x0 += x1; x1 = rotl32(x1, r); x1 ^= x0; }
    TFR(13) TFR(15) TFR(26) TFR(6)   x0 += ks1; x1 += ks2 + 1u;
    TFR(17) TFR(29) TFR(16) TFR(24)  x0 += ks2; x1 += ks0 + 2u;
    TFR(13) TFR(15) TFR(26) TFR(6)   x0 += ks0; x1 += ks1 + 3u;
    TFR(17) TFR(29) TFR(16) TFR(24)  x0 += ks1; x1 += ks2 + 4u;
    TFR(13) TFR(15) TFR(26) TFR(6)   x0 += ks2; x1 += ks0 + 5u;
#undef TFR
    o0 = x0; o1 = x1;
}

__device__ __forceinline__ bool better(float va, int ia, float vb, int ib) {
    return (va > vb) || (va == vb && ia < ib);
}

// ----------------- weight transpose+convert: WT[n][k] = bf16(W[k][n]) ------
__global__ __launch_bounds__(256)
void transpose_bf16(const float* __restrict__ W, unsigned short* __restrict__ WT,
                    int K, int N) {
    __shared__ float t[32][33];
    int kb = blockIdx.x * 32, nb = blockIdx.y * 32;
    int tx = threadIdx.x & 31, ty4 = threadIdx.x >> 5;
#pragma unroll
    for (int p = 0; p < 4; ++p) {
        int ky = ty4 + p * 8;
        t[ky][tx] = W[(long)(kb + ky) * N + nb + tx];
    }
    __syncthreads();
#pragma unroll
    for (int p = 0; p < 4; ++p) {
        int ny = ty4 + p * 8;
        WT[(long)(nb + ny) * K + kb + tx] = f2bf(t[tx][ny]);
    }
}

// WT3[n][0:1024]=hi, [1024:2048]=lo, [2048:3072]=hi  (for policy bf16x3)
__global__ __launch_bounds__(256)
void transpose_split3(const float* __restrict__ W, unsigned short* __restrict__ WT3,
                      int K, int N) {
    __shared__ float t[32][33];
    int kb = blockIdx.x * 32, nb = blockIdx.y * 32;
    int tx = threadIdx.x & 31, ty4 = threadIdx.x >> 5;
#pragma unroll
    for (int p = 0; p < 4; ++p) {
        int ky = ty4 + p * 8;
        t[ky][tx] = W[(long)(kb + ky) * N + nb + tx];
    }
    __syncthreads();
#pragma unroll
    for (int p = 0; p < 4; ++p) {
        int ny = ty4 + p * 8;
        float w = t[tx][ny];
        unsigned short h = f2bf(w);
        unsigned short l = f2bf(w - bf2f(h));
        long base = (long)(nb + ny) * 3072;
        WT3[base + kb + tx] = h;
        WT3[base + 1024 + kb + tx] = l;
        WT3[base + 2048 + kb + tx] = h;
    }
}

// ---------- fp32 -> bf16 hi [+ optional lo split], bit-identical RNE --------
__global__ __launch_bounds__(256)
void cvt_split(const float* __restrict__ src, unsigned short* __restrict__ hi,
               unsigned short* __restrict__ lo, long n8) {
    long i = (long)blockIdx.x * 256 + threadIdx.x;
    long stride = (long)gridDim.x * 256;
    for (; i < n8; i += stride) {
        const float* s = src + i * 8;
        float4v v0 = *(const float4v*)s;
        float4v v1 = *(const float4v*)(s + 4);
        bf16x8 h, l;
#pragma unroll
        for (int e = 0; e < 4; ++e) {
            unsigned short h0 = f2bf(v0[e]);
            h[e] = (short)h0;
            unsigned short h1 = f2bf(v1[e]);
            h[e + 4] = (short)h1;
            if (lo) {
                l[e] = (short)f2bf(v0[e] - bf2f(h0));
                l[e + 4] = (short)f2bf(v1[e] - bf2f(h1));
            }
        }
        *(bf16x8*)&hi[i * 8] = h;
        if (lo) *(bf16x8*)&lo[i * 8] = l;
    }
}

// --------------- pipelined GEMM (bf16 MFMA, B^T weights, dbuf) --------------
// TM = tile rows (128/64). 4 waves 2x2; wave tile (TM/2)x64. BK=64.
// Double-buffered LDS, ONE barrier per K-step: barrier -> stage(next,buf^1)
// -> compute(buf). vmcnt(0)-at-barrier drains loads issued a full compute
// phase earlier. A: dual source (k<K1 -> Av1 [kb=k0&kmod1] else Av2), per-
// source row gathers. EPI=0: C/Cbf write (+gelu,+Cadd). EPI=1: fused
// focus-logit epilogue (gelu . wp2m -> fp64 atomics).
template<int TM, int EPI>
__global__ __launch_bounds__(256)
void gemm_bt(const unsigned short* __restrict__ Av1, long lda1, const int* __restrict__ a1rows,
             const unsigned short* __restrict__ Av2, long lda2, const int* __restrict__ a2rows,
             int K1, int kmod1,
             const unsigned short* __restrict__ WT,
             const float* __restrict__ bias,
             const float* __restrict__ wp2m, double* __restrict__ fl64,
             const float* __restrict__ Cadd,
             float* __restrict__ C,
             unsigned short* __restrict__ Cbf,
             long ldc, int M, int N, int K, int doGelu) {
    constexpr int MT = TM / 32;          // row-frags per wave
    constexpr int WROWS = TM / 2;
    __shared__ unsigned short As[2][TM * 64];
    __shared__ unsigned short Bs[2][128 * 64];
    __shared__ int r1s[TM], r2s[TM];
    int tid = threadIdx.x;
    int bx, by; swz_block(bx, by);
    int row0 = by * TM, col0 = bx * 128;
    if (tid < TM) {
        int gm = row0 + tid; if (gm >= M) gm = M - 1;
        r1s[tid] = a1rows ? a1rows[gm] : gm;
        r2s[tid] = a2rows ? a2rows[gm] : gm;
    }
    int wid = tid >> 6, lane = tid & 63;
    int wr = wid >> 1, wc = wid & 1, llo = lane & 15, lhi = lane >> 4;
    f32x4 acc[MT][4];
#pragma unroll
    for (int i = 0; i < MT; i++)
#pragma unroll
        for (int j = 0; j < 4; j++) acc[i][j] = (f32x4){0.f, 0.f, 0.f, 0.f};
    __syncthreads();                               // r1s/r2s visible

    auto stage = [&](int k0, int b) {
        char* BsB = (char*)Bs[b];
#pragma unroll
        for (int i = 0; i < 4; ++i) {
            int q = tid + (i << 8);
            int r = q >> 3, cs = q & 7, c = cs ^ (r & 7);
            gll16(WT + (long)(col0 + r) * K + (k0 + (c << 3)), BsB + (q << 4));
        }
        bool s1 = (k0 < K1);
        const unsigned short* Ab = s1 ? Av1 : Av2;
        const int* rsel = s1 ? r1s : r2s;
        long lda = s1 ? lda1 : lda2;
        int kb = s1 ? (k0 & kmod1) : (k0 - K1);
        char* AsB = (char*)As[b];
#pragma unroll
        for (int i = 0; i < MT; ++i) {
            int q = tid + (i << 8);
            int r = q >> 3, cs = q & 7, c = cs ^ (r & 7);
            gll16(Ab + (long)rsel[r] * lda + (kb + (c << 3)), AsB + (q << 4));
        }
    };

    stage(0, 0);
    int nIt = K >> 6;
    for (int it = 0; it < nIt; ++it) {
        int cur = it & 1;
        __syncthreads();                 // drains gll into buf[cur] (vmcnt 0)
        if (it + 1 < nIt) stage((it + 1) << 6, cur ^ 1);
        __builtin_amdgcn_sched_barrier(0);   // keep next-tile loads issued early
        char* AsB = (char*)As[cur];
        char* BsB = (char*)Bs[cur];
#pragma unroll
        for (int ks = 0; ks < 2; ++ks) {
            bf16x8 af[MT], bfv[4];
#pragma unroll
            for (int mt = 0; mt < MT; ++mt) {
                int r = wr * WROWS + mt * 16 + llo;
                af[mt] = *(const bf16x8*)(AsB + ((r << 7) + ((((ks << 2) | lhi) ^ (r & 7)) << 4)));
            }
#pragma unroll
            for (int nt = 0; nt < 4; ++nt) {
                int r = wc * 64 + nt * 16 + llo;
                bfv[nt] = *(const bf16x8*)(BsB + ((r << 7) + ((((ks << 2) | lhi) ^ (r & 7)) << 4)));
            }
#pragma unroll
            for (int mt = 0; mt < MT; ++mt)
#pragma unroll
                for (int nt = 0; nt < 4; ++nt)
                    acc[mt][nt] = __builtin_amdgcn_mfma_f32_16x16x32_bf16(
                        af[mt], bfv[nt], acc[mt][nt], 0, 0, 0);
        }
    }
    // epilogue: C/D col=lane&15, row=(lane>>4)*4+reg  [m89-verified]
    if constexpr (EPI == 0) {
#pragma unroll
        for (int mt = 0; mt < MT; ++mt) {
#pragma unroll
            for (int nt = 0; nt < 4; ++nt) {
                int gn = col0 + wc * 64 + nt * 16 + llo;
#pragma unroll
                for (int r = 0; r < 4; ++r) {
                    int gm = row0 + wr * WROWS + mt * 16 + lhi * 4 + r;
                    if (gm >= M) continue;
                    float v = acc[mt][nt][r] + bias[gn];
                    if (doGelu) v = gelu32(v);
                    if (Cadd) v += Cadd[(long)gm * ldc + gn];
                    if (C)   C[(long)gm * ldc + gn] = v;
                    if (Cbf) Cbf[(long)gm * ldc + gn] = f2bf(v);
                }
            }
        }
    } else {
        // fused focus-logit: fl64[m] += sum_n gelu(x)*wp2m[n]
#pragma unroll
        for (int mt = 0; mt < MT; ++mt) {
            double part[4] = {0.0, 0.0, 0.0, 0.0};
#pragma unroll
            for (int nt = 0; nt < 4; ++nt) {
                int gn = col0 + wc * 64 + nt * 16 + llo;
                float b = bias[gn], wn = wp2m[gn];
#pragma unroll
                for (int r = 0; r < 4; ++r) {
                    float x = acc[mt][nt][r] + b;
                    part[r] += (double)gelu32(x) * (double)wn;
                }
            }
#pragma unroll
            for (int r = 0; r < 4; ++r) {
                double v = part[r];
                v += __shfl_xor(v, 1);
                v += __shfl_xor(v, 2);
                v += __shfl_xor(v, 4);
                v += __shfl_xor(v, 8);
                if (llo == 0)
                    atomicAdd(&fl64[row0 + wr * WROWS + mt * 16 + lhi * 4 + r], v);
            }
        }
    }
}

__global__ void flbuild_kernel(const double* __restrict__ fl64,
                               const float* __restrict__ wp2m,
                               const int* __restrict__ amask,
                               float* __restrict__ fl32) {
    int m = blockIdx.x * 256 + threadIdx.x;
    fl32[m] = (amask[m] == 0) ? -1e9f : (float)(fl64[m] + (double)wp2m[1024]);
}

// --------------------------- small kernels ---------------------------------
__global__ void wp2mean_kernel(const float* __restrict__ Wp2,
                               const float* __restrict__ bp2,
                               float* __restrict__ outv) {
    __shared__ double sb[256];
    int r = blockIdx.x, tid = threadIdx.x;
    const float* src = (r < 1024) ? (Wp2 + (size_t)r * 1024) : bp2;
    double s = 0.0;
    for (int k = tid; k < 1024; k += 256) s += (double)src[k];
    sb[tid] = s; __syncthreads();
    for (int off = 128; off > 0; off >>= 1) {
        if (tid < off) sb[tid] += sb[tid + off];
        __syncthreads();
    }
    if (tid == 0) outv[r] = (float)(sb[0] * (1.0 / 1024.0));
}

__global__ void rootmean_kernel(const float* __restrict__ root, float* __restrict__ rmean,
                                unsigned short* __restrict__ rmean_bf) {
    int b = blockIdx.x;
    int h = blockIdx.y * 256 + threadIdx.x;
    const float* base = root + (size_t)b * SHC + h;
    double s = 0.0;
    for (int ss = 0; ss < SEQ; ss++) s += (double)base[(size_t)ss * HDIM];
    float v = (float)(s * (1.0 / 1024.0));
    rmean[b * HDIM + h] = v;
    rmean_bf[b * HDIM + h] = f2bf(v);
}

__global__ __launch_bounds__(256)
void ctrl_fc1(const float* __restrict__ root, const float* __restrict__ W,
              const float* __restrict__ b1, float* __restrict__ T1) {
    __shared__ double red[16][17];
    int ni = threadIdx.x & 15, kt = threadIdx.x >> 4;
    int n = blockIdx.x * 16 + ni;
    double accb[16];
#pragma unroll
    for (int bb = 0; bb < 16; ++bb) accb[bb] = 0.0;
    for (int k = kt * 64; k < kt * 64 + 64; ++k) {
        double w = (double)W[(long)k * 1024 + n];
#pragma unroll
        for (int bb = 0; bb < 16; ++bb)
            accb[bb] = fma((double)root[(long)bb * SHC + k], w, accb[bb]);
    }
    for (int bb = 0; bb < 16; ++bb) {
        red[kt][ni] = accb[bb];
        __syncthreads();
        if (kt == 0) {
            double s = 0.0;
            for (int q = 0; q < 16; ++q) s += red[q][ni];
            double x = s + (double)b1[n];
            T1[bb * 1024 + n] = (float)(0.5 * x * (1.0 + erf(x * 0.70710678118654752440)));
        }
        __syncthreads();
    }
}

__global__ void ctrl_fc2(const float* __restrict__ T1, const float* __restrict__ W2,
                         const float* __restrict__ b2, float* __restrict__ logits) {
    __shared__ double sb[256];
    int bn = blockIdx.x;
    int b = bn / 5, n = bn % 5;
    double s = 0.0;
    for (int k = threadIdx.x; k < 1024; k += 256)
        s += (double)T1[b * 1024 + k] * (double)W2[k * 5 + n];
    sb[threadIdx.x] = s; __syncthreads();
    for (int off = 128; off > 0; off >>= 1) {
        if (threadIdx.x < off) sb[threadIdx.x] += sb[threadIdx.x + off];
        __syncthreads();
    }
    if (threadIdx.x == 0) logits[b * 5 + n] = (float)(sb[0] + (double)b2[n]);
}

__global__ void sims_kernel(const float* __restrict__ logits, int* __restrict__ sims) {
    int b = threadIdx.x;
    if (b >= BATCH) return;
    float best = logits[b * 5 + 0]; int biv = 0;
    for (int i = 1; i < 5; i++) {
        float v = logits[b * 5 + i];
        if (v > best) { best = v; biv = i; }
    }
    const int opt[5] = {10, 25, 50, 75, 100};
    sims[b] = opt[biv];
}

// Per (t,b): JAX PARTITIONABLE threefry (byte-identical to rounds 5-10)
__global__ void gumbel_kernel(const float* __restrict__ fl,
                              int* __restrict__ idxj, int* __restrict__ vidx) {
    __shared__ float sv[256][3];
    __shared__ int   si[256][3];
    int blk = blockIdx.x;           // c = t*16+b
    int t = blk >> 4, b = blk & 15;
    uint32_t kk0, kk1;
    threefry(0u, 42u, 0u, (uint32_t)t, kk0, kk1);   // fold_in(key(42), t)
    int tid = threadIdx.x;
    float bv[3] = {-INFINITY, -INFINITY, -INFINITY};
    int   bi[3] = {0x7FFFFFFF, 0x7FFFFFFF, 0x7FFFFFFF};
    for (int s = tid; s < SEQ; s += 256) {
        uint32_t m = (uint32_t)(b * SEQ + s);
        uint32_t y0, y1;
        threefry(kk0, kk1, 0u, m, y0, y1);
        uint32_t bits = y0 ^ y1;
        float f = __uint_as_float((bits >> 9) | 0x3F800000u) - 1.0f;
        float u = fmaxf(1.17549435e-38f, f);
        float l1 = (float)log((double)u);
        float l2 = (float)log(-(double)l1);
        float g  = -l2;
        float val = fl[b * SEQ + s] + g;
        if (better(val, s, bv[2], bi[2])) {
            bv[2] = val; bi[2] = s;
            if (better(bv[2], bi[2], bv[1], bi[1])) {
                float tv = bv[1]; int ti = bi[1];
                bv[1] = bv[2]; bi[1] = bi[2]; bv[2] = tv; bi[2] = ti;
            }
            if (better(bv[1], bi[1], bv[0], bi[0])) {
                float tv = bv[0]; int ti = bi[0];
                bv[0] = bv[1]; bi[0] = bi[1]; bv[1] = tv; bi[1] = ti;
            }
        }
    }
    sv[tid][0] = bv[0]; sv[tid][1] = bv[1]; sv[tid][2] = bv[2];
    si[tid][0] = bi[0]; si[tid][1] = bi[1]; si[tid][2] = bi[2];
    __syncthreads();
    for (int off = 128; off > 0; off >>= 1) {
        if (tid < off) {
            float av[3] = {sv[tid][0], sv[tid][1], sv[tid][2]};
            int   ai[3] = {si[tid][0], si[tid][1], si[tid][2]};
            float cv[3] = {sv[tid + off][0], sv[tid + off][1], sv[tid + off][2]};
            int   ci[3] = {si[tid + off][0], si[tid + off][1], si[tid + off][2]};
            float rv[3]; int ri[3]; int pa = 0, pb = 0;
#pragma unroll
            for (int r = 0; r < 3; r++) {
                if (better(av[pa], ai[pa], cv[pb], ci[pb])) { rv[r] = av[pa]; ri[r] = ai[pa]; pa++; }
                else                                        { rv[r] = cv[pb]; ri[r] = ci[pb]; pb++; }
            }
            sv[tid][0] = rv[0]; sv[tid][1] = rv[1]; sv[tid][2] = rv[2];
            si[tid][0] = ri[0]; si[tid][1] = ri[1]; si[tid][2] = ri[2];
        }
        __syncthreads();
    }
    if (tid == 0) {
        idxj[0 * NCHAIN + blk] = b * SEQ + si[0][0];
        idxj[1 * NCHAIN + blk] = b * SEQ + si[0][1];
        idxj[2 * NCHAIN + blk] = b * SEQ + si[0][2];
        vidx[blk] = b;
    }
}

__global__ void meaninit_kernel(const float* __restrict__ rmean, float* __restrict__ mean_cur,
                                unsigned short* __restrict__ mc_bf) {
    int e = blockIdx.x * 256 + threadIdx.x;
    int c = e >> 10, hh = e & 1023;
    float v = rmean[(c & 15) * HDIM + hh];
    mean_cur[e] = v;
    mc_bf[e] = f2bf(v);
}

__global__ void meanupd_kernel(const float* __restrict__ NSj, const float* __restrict__ root,
                               const int* __restrict__ idx, float* __restrict__ mean_cur,
                               unsigned short* __restrict__ mc_bf) {
    int e = blockIdx.x * 256 + threadIdx.x;
    int c = e >> 10, hh = e & 1023;
    int r = idx[c];
    double m = (double)mean_cur[e] +
               ((double)NSj[e] - (double)root[(size_t)r * HDIM + hh]) * (1.0 / 1024.0);
    float v = (float)m;
    mean_cur[e] = v;
    mc_bf[e] = f2bf(v);
}

__global__ void valdot_kernel(const float* __restrict__ HV, const float* __restrict__ Wav2,
                              const float* __restrict__ bav2, float* __restrict__ w) {
    __shared__ double sb[256];
    int c = blockIdx.x, tid = threadIdx.x;
    double s = 0.0;
    for (int k = tid; k < HDIM; k += 256) s += (double)HV[(size_t)c * HDIM + k] * (double)Wav2[k];
    sb[tid] = s; __syncthreads();
    for (int off = 128; off > 0; off >>= 1) {
        if (tid < off) sb[tid] += sb[tid + off];
        __syncthreads();
    }
    if (tid == 0) {
        double v = sb[0] + (double)bav2[0];
        w[c] = (float)(1.0 / (1.0 + exp(-v)));
    }
}

__global__ void wsum_kernel(const float* __restrict__ w, const int* __restrict__ sims,
                            double* __restrict__ Wsum) {
    int b = threadIdx.x;
    if (b >= BATCH) return;
    int sb = sims[b];
    double s = 0.0;
    for (int t = 0; t < sb; t++) s += (double)w[t * BATCH + b];
    Wsum[b] = s;
}

__global__ void accinit_kernel(const float* __restrict__ root, const double* __restrict__ Wsum,
                               float* __restrict__ acc) {
    size_t e = (size_t)blockIdx.x * 256 + threadIdx.x;
    int b = (int)(e >> 20);
    acc[e] = (float)((1.0 + Wsum[b]) * (double)root[e]);
}

__global__ __launch_bounds__(256)
void corrections_atomic(const float* __restrict__ NS, const float* __restrict__ root,
                        const float* __restrict__ w, const int* __restrict__ sims,
                        const int* __restrict__ idxj, float* __restrict__ acc) {
    int blk = blockIdx.x;                // 0..4799
    int j = blk / NCHAIN, c = blk % NCHAIN;
    int b = c & 15, t = c >> 4;
    if (t >= sims[b]) return;
    float wv = w[c];
    int row = idxj[j * NCHAIN + c];
    const float* ns = NS + ((long)j * NCHAIN + c) * 1024;
    const float* rt = root + (long)row * 1024;
    float* ac = acc + (long)row * 1024;
    for (int h = threadIdx.x; h < 1024; h += 256)
        atomicAdd(&ac[h], wv * (ns[h] - rt[h]));
}

// ------------------------------- launch ------------------------------------
extern "C" void kernel_launch(void* const* d_in, const int* in_sizes, int n_in,
                              void* d_out, int out_size, void* d_ws, size_t ws_size,
                              hipStream_t stream) {
    (void)in_sizes; (void)n_in; (void)out_size; (void)ws_size;
    const float* root = (const float*)d_in[0];
    const int*   amask = (const int*)d_in[1];
    const float* Wsc1 = (const float*)d_in[2];  const float* bsc1 = (const float*)d_in[3];
    const float* Wsc2 = (const float*)d_in[4];  const float* bsc2 = (const float*)d_in[5];
    const float* Wp1  = (const float*)d_in[6];  const float* bp1  = (const float*)d_in[7];
    const float* Wp2  = (const float*)d_in[8];  const float* bp2  = (const float*)d_in[9];
    const float* Wt1  = (const float*)d_in[10]; const float* bt1  = (const float*)d_in[11];
    const float* Wt2  = (const float*)d_in[12]; const float* bt2  = (const float*)d_in[13];
    const float* Wav1 = (const float*)d_in[14]; const float* bav1 = (const float*)d_in[15];
    const float* Wav2 = (const float*)d_in[16]; const float* bav2 = (const float*)d_in[17];
    const float* Wg1  = (const float*)d_in[18]; const float* bg1  = (const float*)d_in[19];
    const float* Wg2  = (const float*)d_in[20]; const float* bg2  = (const float*)d_in[21];
    float* out = (float*)d_out;

    // ---- workspace carving (~123.6 MB; < round-10's proven 127.8 MB) ----
    char* p = (char*)d_ws;
    auto carve = [&](size_t nbytes) -> void* {
        void* r = (void*)p; p += (nbytes + 255) & ~(size_t)255; return r;
    };
    float*          mean_cur = (float*)carve((size_t)NCHAIN * HDIM * 4);
    unsigned short* H1bf     = (unsigned short*)carve((size_t)NCHAIN * HDIM * 2);
    float*          Hav      = (float*)carve((size_t)NCHAIN * HDIM * 4);
    float*          NS       = (float*)carve((size_t)3 * NCHAIN * HDIM * 4);
    unsigned short* h_bf     = (unsigned short*)mean_cur;  // step-9 alias (33.55MB<=36MB)
    unsigned short* WT3      = (unsigned short*)NS;        // policy weights: dead before NS written
    unsigned short* WTt1  = (unsigned short*)carve((size_t)1024 * 2048 * 2);
    unsigned short* WTt2  = (unsigned short*)carve((size_t)1024 * 1024 * 2);
    unsigned short* WTav1 = (unsigned short*)carve((size_t)1024 * 2048 * 2);
    unsigned short* WTg1  = (unsigned short*)carve((size_t)1024 * 2048 * 2);
    unsigned short* WTg2  = (unsigned short*)carve((size_t)1024 * 1024 * 2);
    float*  rmean  = (float*)carve(BATCH * HDIM * 4);
    float*  T1     = (float*)carve(BATCH * HDIM * 4);
    float*  logits = (float*)carve(128 * 4);
    float*  wp2m   = (float*)carve(1040 * 4);
    double* fl64   = (double*)carve((size_t)BATCH * SEQ * 8);
    float*  fl32   = (float*)carve(BATCH * SEQ * 4);
    float*  wbuf   = (float*)carve(NCHAIN * 4);
    double* Wsumd  = (double*)carve(64 * 8);
    int*    sims   = (int*)carve(64 * 4);
    int*    idxj   = (int*)carve(3 * NCHAIN * 4);
    int*    vidx   = (int*)carve(NCHAIN * 4);
    unsigned short* root_bf     = (unsigned short*)carve((size_t)BATCH * SEQ * HDIM * 2);
    unsigned short* acc_bf      = (unsigned short*)carve((size_t)BATCH * SEQ * HDIM * 2);
    unsigned short* root_lo     = acc_bf;   // policy (step 4) dead before acc_bf (step 8b)
    unsigned short* mean_cur_bf = (unsigned short*)carve((size_t)NCHAIN * HDIM * 2);
    unsigned short* rmean_bf    = (unsigned short*)carve(BATCH * HDIM * 2);

    const long NTOT8 = (long)BATCH * SEQ * HDIM / 8;
    const int  KBIG = 1 << 30, KMA = 0x7FFFFFFF;

    // 1) weight transposes (+ policy hi/lo triple-stack)
    transpose_bf16<<<dim3(2048 / 32, 1024 / 32), 256, 0, stream>>>(Wt1, WTt1, 2048, 1024);
    transpose_bf16<<<dim3(1024 / 32, 1024 / 32), 256, 0, stream>>>(Wt2, WTt2, 1024, 1024);
    transpose_bf16<<<dim3(2048 / 32, 1024 / 32), 256, 0, stream>>>(Wav1, WTav1, 2048, 1024);
    transpose_bf16<<<dim3(2048 / 32, 1024 / 32), 256, 0, stream>>>(Wg1, WTg1, 2048, 1024);
    transpose_bf16<<<dim3(1024 / 32, 1024 / 32), 256, 0, stream>>>(Wg2, WTg2, 1024, 1024);
    transpose_split3<<<dim3(32, 32), 256, 0, stream>>>(Wp1, WT3, 1024, 1024);
    // 1b) root -> bf16 hi+lo once (root_lo aliases acc_bf)
    cvt_split<<<2048, 256, 0, stream>>>(root, root_bf, root_lo, NTOT8);
    // 2) wp2 means, root mean
    wp2mean_kernel<<<1025, 256, 0, stream>>>(Wp2, bp2, wp2m);
    rootmean_kernel<<<dim3(BATCH, HDIM / 256), 256, 0, stream>>>(root, rmean, rmean_bf);
    // 3) controller (fp64) -> sims
    ctrl_fc1<<<64, 256, 0, stream>>>(root, Wsc1, bsc1, T1);
    ctrl_fc2<<<80, 256, 0, stream>>>(T1, Wsc2, bsc2, logits);
    sims_kernel<<<1, 64, 0, stream>>>(logits, sims);
    // 4) policy as pipelined K=3072 GEMM ([hi|hi|lo]) + fused fl epilogue
    hipMemsetAsync(fl64, 0, (size_t)BATCH * SEQ * 8, stream);
    gemm_bt<128, 1><<<dim3(8, 128), 256, 0, stream>>>(
        root_bf, 1024, nullptr, root_lo, 1024, nullptr, 2048, 1023,
        WT3, bp1, wp2m, fl64, nullptr, nullptr, nullptr, 1024,
        BATCH * SEQ, 1024, 3072, 0);
    flbuild_kernel<<<BATCH * SEQ / 256, 256, 0, stream>>>(fl64, wp2m, amask, fl32);
    // 5) gumbel top-3 (partitionable threefry, unchanged)
    gumbel_kernel<<<NCHAIN, 256, 0, stream>>>(fl32, idxj, vidx);
    // 6) transitions (TM=64, pipelined)
    meaninit_kernel<<<NCHAIN * HDIM / 256, 256, 0, stream>>>(rmean, mean_cur, mean_cur_bf);
    for (int j = 0; j < 3; j++) {
        gemm_bt<64, 0><<<dim3(8, 25), 256, 0, stream>>>(
            mean_cur_bf, 1024, nullptr, root_bf, 1024, idxj + j * NCHAIN, 1024, KMA,
            WTt1, bt1, nullptr, nullptr, nullptr, nullptr, H1bf, 1024,
            NCHAIN, 1024, 2048, 1);
        gemm_bt<64, 0><<<dim3(8, 25), 256, 0, stream>>>(
            H1bf, 1024, nullptr, nullptr, 0, nullptr, KBIG, KMA,
            WTt2, bt2, nullptr, nullptr, nullptr, NS + (size_t)j * NCHAIN * HDIM, nullptr,
            1024, NCHAIN, 1024, 1024, 0);
        meanupd_kernel<<<NCHAIN * HDIM / 256, 256, 0, stream>>>(
            NS + (size_t)j * NCHAIN * HDIM, root, idxj + j * NCHAIN, mean_cur, mean_cur_bf);
    }
    // 7) action value -> w -> Wsum
    gemm_bt<64, 0><<<dim3(8, 25), 256, 0, stream>>>(
        rmean_bf, 1024, vidx, mean_cur_bf, 1024, nullptr, 1024, KMA,
        WTav1, bav1, nullptr, nullptr, nullptr, Hav, nullptr, 1024,
        NCHAIN, 1024, 2048, 1);
    valdot_kernel<<<NCHAIN, 256, 0, stream>>>(Hav, Wav2, bav2, wbuf);
    wsum_kernel<<<1, 64, 0, stream>>>(wbuf, sims, Wsumd);
    // 8) acc (in d_out): init + parallel corrections + bf16 copy
    accinit_kernel<<<(BATCH * SEQ * HDIM) / 256, 256, 0, stream>>>(root, Wsumd, out);
    corrections_atomic<<<3 * NCHAIN, 256, 0, stream>>>(NS, root, wbuf, sims, idxj, out);
    cvt_split<<<2048, 256, 0, stream>>>(out, acc_bf, nullptr, NTOT8);
    // 9) aggregation (TM=128, pipelined)
    gemm_bt<128, 0><<<dim3(8, 128), 256, 0, stream>>>(
        root_bf, 1024, nullptr, acc_bf, 1024, nullptr, 1024, KMA,
        WTg1, bg1, nullptr, nullptr, nullptr, nullptr, h_bf, 1024,
        BATCH * SEQ, 1024, 2048, 1);
    gemm_bt<128, 0><<<dim3(8, 128), 256, 0, stream>>>(
        h_bf, 1024, nullptr, nullptr, 0, nullptr, KBIG, KMA,
        WTg2, bg2, nullptr, nullptr, root, out, nullptr, 1024,
        BATCH * SEQ, 1024, 1024, 0);
}

// Round 12
// 876.013 us; speedup vs baseline: 1.2719x; 1.2719x over previous
//
#include <hip/hip_runtime.h>
#include <hip/hip_bf16.h>
#include <cstdint>
#include <math.h>

// ---------------------------------------------------------------------------
// AdaptiveMCTSReasoner  B=16, S=1024, H=1024, MAX_SIMS=100, K_FOCUS=3
// Round 12: R11's pipelined dbuf GEMM, but 8 waves/block (512 thr) so the
// 64KB-LDS double buffer keeps 16 waves/CU (2 blk x 8 waves) instead of
// R11's 8 (2 blk x 4). Wave grid 2x4, wave tile (TM/2)x32. Everything else
// (swizzle, dual-source+gather, EPI variants, policy-as-K=3072, launch
// order, selection path) identical to R11 (passed, absmax 0.5).
// ---------------------------------------------------------------------------

#define SEQ 1024
#define BATCH 16
#define HDIM 1024
#define NSIM 100
#define NCHAIN (NSIM * BATCH)   // 1600
#define SHC (SEQ * HDIM)

typedef short bf16x8 __attribute__((ext_vector_type(8)));
typedef float f32x4 __attribute__((ext_vector_type(4)));
typedef float float4v __attribute__((ext_vector_type(4)));

__device__ __forceinline__ unsigned short f2bf(float f) {
    union { float f; uint32_t u; } c; c.f = f;
    uint32_t u = c.u;
    return (unsigned short)((u + 0x7FFFu + ((u >> 16) & 1u)) >> 16);   // RNE
}
__device__ __forceinline__ float bf2f(unsigned short h) {
    union { uint32_t u; float f; } c; c.u = ((uint32_t)h) << 16;
    return c.f;
}

__device__ __forceinline__ void gll16(const void* g, void* l) {
    __builtin_amdgcn_global_load_lds(
        (const __attribute__((address_space(1))) void*)g,
        (__attribute__((address_space(3))) void*)l, 16, 0, 0);
}

__device__ __forceinline__ float gelu32(float x) {
    return 0.5f * x * (1.0f + erff(x * 0.70710678f));
}

// XCD-aware bijective swizzle (requires nwg % 8 == 0; all our grids qualify)
__device__ __forceinline__ void swz_block(int& bx, int& by) {
    int gx = gridDim.x;
    int h = blockIdx.y * gx + blockIdx.x;
    int nwg = gx * gridDim.y;
    int l = (h & 7) * (nwg >> 3) + (h >> 3);
    bx = l % gx; by = l / gx;
}

// ------------------------------- threefry ----------------------------------
__device__ __forceinline__ uint32_t rotl32(uint32_t v, int r) {
    return (v << r) | (v >> (32 - r));
}

__device__ __forceinline__ void threefry(uint32_t k0, uint32_t k1,
                                         uint32_t c0, uint32_t c1,
                                         uint32_t& o0, uint32_t& o1) {
    uint32_t ks0 = k0, ks1 = k1, ks2 = k0 ^ k1 ^ 0x1BD11BDAu;
    uint32_t x0 = c0 + ks0, x1 = c1 + ks1;
#define TFR(r) { x0 += x1; x1 = rotl32(x1, r); x1 ^= x0; }
    TFR(13) TFR(15) TFR(26) TFR(6)   x0 += ks1; x1 += ks2 + 1u;
    TFR(17) TFR(29) TFR(16) TFR(24)  x0 += ks2; x1 += ks0 + 2u;
    TFR(13) TFR(15) TFR(26) TFR(6)   x0 += ks0; x1 += ks1 + 3u;
    TFR(17) TFR(29) TFR(16) TFR(24)  x0 += ks1; x1 += ks2 + 4u;
    TFR(13) TFR(15) TFR(26) TFR(6)   x0 += ks2; x1 += ks0 + 5u;
#undef TFR
    o0 = x0; o1 = x1;
}

__device__ __forceinline__ bool better(float va, int ia, float vb, int ib) {
    return (va > vb) || (va == vb && ia < ib);
}

// ----------------- weight transpose+convert: WT[n][k] = bf16(W[k][n]) ------
__global__ __launch_bounds__(256)
void transpose_bf16(const float* __restrict__ W, unsigned short* __restrict__ WT,
                    int K, int N) {
    __shared__ float t[32][33];
    int kb = blockIdx.x * 32, nb = blockIdx.y * 32;
    int tx = threadIdx.x & 31, ty4 = threadIdx.x >> 5;
#pragma unroll
    for (int p = 0; p < 4; ++p) {
        int ky = ty4 + p * 8;
        t[ky][tx] = W[(long)(kb + ky) * N + nb + tx];
    }
    __syncthreads();
#pragma unroll
    for (int p = 0; p < 4; ++p) {
        int ny = ty4 + p * 8;
        WT[(long)(nb + ny) * K + kb + tx] = f2bf(t[tx][ny]);
    }
}

// WT3[n][0:1024]=hi, [1024:2048]=lo, [2048:3072]=hi  (for policy bf16x3)
__global__ __launch_bounds__(256)
void transpose_split3(const float* __restrict__ W, unsigned short* __restrict__ WT3,
                      int K, int N) {
    __shared__ float t[32][33];
    int kb = blockIdx.x * 32, nb = blockIdx.y * 32;
    int tx = threadIdx.x & 31, ty4 = threadIdx.x >> 5;
#pragma unroll
    for (int p = 0; p < 4; ++p) {
        int ky = ty4 + p * 8;
        t[ky][tx] = W[(long)(kb + ky) * N + nb + tx];
    }
    __syncthreads();
#pragma unroll
    for (int p = 0; p < 4; ++p) {
        int ny = ty4 + p * 8;
        float w = t[tx][ny];
        unsigned short h = f2bf(w);
        unsigned short l = f2bf(w - bf2f(h));
        long base = (long)(nb + ny) * 3072;
        WT3[base + kb + tx] = h;
        WT3[base + 1024 + kb + tx] = l;
        WT3[base + 2048 + kb + tx] = h;
    }
}

// ---------- fp32 -> bf16 hi [+ optional lo split], bit-identical RNE --------
__global__ __launch_bounds__(256)
void cvt_split(const float* __restrict__ src, unsigned short* __restrict__ hi,
               unsigned short* __restrict__ lo, long n8) {
    long i = (long)blockIdx.x * 256 + threadIdx.x;
    long stride = (long)gridDim.x * 256;
    for (; i < n8; i += stride) {
        const float* s = src + i * 8;
        float4v v0 = *(const float4v*)s;
        float4v v1 = *(const float4v*)(s + 4);
        bf16x8 h, l;
#pragma unroll
        for (int e = 0; e < 4; ++e) {
            unsigned short h0 = f2bf(v0[e]);
            h[e] = (short)h0;
            unsigned short h1 = f2bf(v1[e]);
            h[e + 4] = (short)h1;
            if (lo) {
                l[e] = (short)f2bf(v0[e] - bf2f(h0));
                l[e + 4] = (short)f2bf(v1[e] - bf2f(h1));
            }
        }
        *(bf16x8*)&hi[i * 8] = h;
        if (lo) *(bf16x8*)&lo[i * 8] = l;
    }
}

// --------- pipelined GEMM (bf16 MFMA, B^T weights, dbuf, 8 waves) ----------
// TM = tile rows (128/64). 512 threads = 8 waves as 2x4; wave tile (TM/2)x32.
// BK=64. Double-buffered LDS, ONE barrier per K-step: barrier ->
// stage(next, buf^1) -> compute(buf). A: dual source (k<K1 -> Av1 with
// kb=k0&kmod1, else Av2), per-source row gathers. EPI=0: C/Cbf write
// (+gelu,+Cadd). EPI=1: fused focus-logit epilogue.
template<int TM, int EPI>
__global__ __launch_bounds__(512)
void gemm_bt(const unsigned short* __restrict__ Av1, long lda1, const int* __restrict__ a1rows,
             const unsigned short* __restrict__ Av2, long lda2, const int* __restrict__ a2rows,
             int K1, int kmod1,
             const unsigned short* __restrict__ WT,
             const float* __restrict__ bias,
             const float* __restrict__ wp2m, double* __restrict__ fl64,
             const float* __restrict__ Cadd,
             float* __restrict__ C,
             unsigned short* __restrict__ Cbf,
             long ldc, int M, int N, int K, int doGelu) {
    constexpr int MT = TM / 32;          // row-frags per wave (wave rows = TM/2)
    constexpr int WROWS = TM / 2;
    constexpr int ALD = TM / 64;         // A gll per thread per K-step
    __shared__ unsigned short As[2][TM * 64];
    __shared__ unsigned short Bs[2][128 * 64];
    __shared__ int r1s[TM], r2s[TM];
    int tid = threadIdx.x;
    int bx, by; swz_block(bx, by);
    int row0 = by * TM, col0 = bx * 128;
    if (tid < TM) {
        int gm = row0 + tid; if (gm >= M) gm = M - 1;
        r1s[tid] = a1rows ? a1rows[gm] : gm;
        r2s[tid] = a2rows ? a2rows[gm] : gm;
    }
    int wid = tid >> 6, lane = tid & 63;
    int wr = wid >> 2, wc = wid & 3;          // 2 x 4 wave grid
    int llo = lane & 15, lhi = lane >> 4;
    f32x4 acc[MT][2];
#pragma unroll
    for (int i = 0; i < MT; i++)
#pragma unroll
        for (int j = 0; j < 2; j++) acc[i][j] = (f32x4){0.f, 0.f, 0.f, 0.f};
    __syncthreads();                               // r1s/r2s visible

    auto stage = [&](int k0, int b) {
        char* BsB = (char*)Bs[b];
#pragma unroll
        for (int i = 0; i < 2; ++i) {
            int q = tid + (i << 9);
            int r = q >> 3, cs = q & 7, c = cs ^ (r & 7);
            gll16(WT + (long)(col0 + r) * K + (k0 + (c << 3)), BsB + (q << 4));
        }
        bool s1 = (k0 < K1);
        const unsigned short* Ab = s1 ? Av1 : Av2;
        const int* rsel = s1 ? r1s : r2s;
        long lda = s1 ? lda1 : lda2;
        int kb = s1 ? (k0 & kmod1) : (k0 - K1);
        char* AsB = (char*)As[b];
#pragma unroll
        for (int i = 0; i < ALD; ++i) {
            int q = tid + (i << 9);
            int r = q >> 3, cs = q & 7, c = cs ^ (r & 7);
            gll16(Ab + (long)rsel[r] * lda + (kb + (c << 3)), AsB + (q << 4));
        }
    };

    stage(0, 0);
    int nIt = K >> 6;
    for (int it = 0; it < nIt; ++it) {
        int cur = it & 1;
        __syncthreads();                 // drains gll into buf[cur]
        if (it + 1 < nIt) stage((it + 1) << 6, cur ^ 1);
        __builtin_amdgcn_sched_barrier(0);   // keep next-tile loads issued early
        char* AsB = (char*)As[cur];
        char* BsB = (char*)Bs[cur];
#pragma unroll
        for (int ks = 0; ks < 2; ++ks) {
            bf16x8 af[MT], bfv[2];
#pragma unroll
            for (int mt = 0; mt < MT; ++mt) {
                int r = wr * WROWS + mt * 16 + llo;
                af[mt] = *(const bf16x8*)(AsB + ((r << 7) + ((((ks << 2) | lhi) ^ (r & 7)) << 4)));
            }
#pragma unroll
            for (int nt = 0; nt < 2; ++nt) {
                int r = wc * 32 + nt * 16 + llo;
                bfv[nt] = *(const bf16x8*)(BsB + ((r << 7) + ((((ks << 2) | lhi) ^ (r & 7)) << 4)));
            }
#pragma unroll
            for (int mt = 0; mt < MT; ++mt)
#pragma unroll
                for (int nt = 0; nt < 2; ++nt)
                    acc[mt][nt] = __builtin_amdgcn_mfma_f32_16x16x32_bf16(
                        af[mt], bfv[nt], acc[mt][nt], 0, 0, 0);
        }
    }
    // epilogue: C/D col=lane&15, row=(lane>>4)*4+reg  [m89-verified]
    if constexpr (EPI == 0) {
#pragma unroll
        for (int mt = 0; mt < MT; ++mt) {
#pragma unroll
            for (int nt = 0; nt < 2; ++nt) {
                int gn = col0 + wc * 32 + nt * 16 + llo;
#pragma unroll
                for (int r = 0; r < 4; ++r) {
                    int gm = row0 + wr * WROWS + mt * 16 + lhi * 4 + r;
                    if (gm >= M) continue;
                    float v = acc[mt][nt][r] + bias[gn];
                    if (doGelu) v = gelu32(v);
                    if (Cadd) v += Cadd[(long)gm * ldc + gn];
                    if (C)   C[(long)gm * ldc + gn] = v;
                    if (Cbf) Cbf[(long)gm * ldc + gn] = f2bf(v);
                }
            }
        }
    } else {
        // fused focus-logit: fl64[m] += sum_n gelu(x)*wp2m[n]
#pragma unroll
        for (int mt = 0; mt < MT; ++mt) {
            double part[4] = {0.0, 0.0, 0.0, 0.0};
#pragma unroll
            for (int nt = 0; nt < 2; ++nt) {
                int gn = col0 + wc * 32 + nt * 16 + llo;
                float b = bias[gn], wn = wp2m[gn];
#pragma unroll
                for (int r = 0; r < 4; ++r) {
                    float x = acc[mt][nt][r] + b;
                    part[r] += (double)gelu32(x) * (double)wn;
                }
            }
#pragma unroll
            for (int r = 0; r < 4; ++r) {
                double v = part[r];
                v += __shfl_xor(v, 1);
                v += __shfl_xor(v, 2);
                v += __shfl_xor(v, 4);
                v += __shfl_xor(v, 8);
                if (llo == 0)
                    atomicAdd(&fl64[row0 + wr * WROWS + mt * 16 + lhi * 4 + r], v);
            }
        }
    }
}

__global__ void flbuild_kernel(const double* __restrict__ fl64,
                               const float* __restrict__ wp2m,
                               const int* __restrict__ amask,
                               float* __restrict__ fl32) {
    int m = blockIdx.x * 256 + threadIdx.x;
    fl32[m] = (amask[m] == 0) ? -1e9f : (float)(fl64[m] + (double)wp2m[1024]);
}

// --------------------------- small kernels ---------------------------------
__global__ void wp2mean_kernel(const float* __restrict__ Wp2,
                               const float* __restrict__ bp2,
                               float* __restrict__ outv) {
    __shared__ double sb[256];
    int r = blockIdx.x, tid = threadIdx.x;
    const float* src = (r < 1024) ? (Wp2 + (size_t)r * 1024) : bp2;
    double s = 0.0;
    for (int k = tid; k < 1024; k += 256) s += (double)src[k];
    sb[tid] = s; __syncthreads();
    for (int off = 128; off > 0; off >>= 1) {
        if (tid < off) sb[tid] += sb[tid + off];
        __syncthreads();
    }
    if (tid == 0) outv[r] = (float)(sb[0] * (1.0 / 1024.0));
}

__global__ void rootmean_kernel(const float* __restrict__ root, float* __restrict__ rmean,
                                unsigned short* __restrict__ rmean_bf) {
    int b = blockIdx.x;
    int h = blockIdx.y * 256 + threadIdx.x;
    const float* base = root + (size_t)b * SHC + h;
    double s = 0.0;
    for (int ss = 0; ss < SEQ; ss++) s += (double)base[(size_t)ss * HDIM];
    float v = (float)(s * (1.0 / 1024.0));
    rmean[b * HDIM + h] = v;
    rmean_bf[b * HDIM + h] = f2bf(v);
}

__global__ __launch_bounds__(256)
void ctrl_fc1(const float* __restrict__ root, const float* __restrict__ W,
              const float* __restrict__ b1, float* __restrict__ T1) {
    __shared__ double red[16][17];
    int ni = threadIdx.x & 15, kt = threadIdx.x >> 4;
    int n = blockIdx.x * 16 + ni;
    double accb[16];
#pragma unroll
    for (int bb = 0; bb < 16; ++bb) accb[bb] = 0.0;
    for (int k = kt * 64; k < kt * 64 + 64; ++k) {
        double w = (double)W[(long)k * 1024 + n];
#pragma unroll
        for (int bb = 0; bb < 16; ++bb)
            accb[bb] = fma((double)root[(long)bb * SHC + k], w, accb[bb]);
    }
    for (int bb = 0; bb < 16; ++bb) {
        red[kt][ni] = accb[bb];
        __syncthreads();
        if (kt == 0) {
            double s = 0.0;
            for (int q = 0; q < 16; ++q) s += red[q][ni];
            double x = s + (double)b1[n];
            T1[bb * 1024 + n] = (float)(0.5 * x * (1.0 + erf(x * 0.70710678118654752440)));
        }
        __syncthreads();
    }
}

__global__ void ctrl_fc2(const float* __restrict__ T1, const float* __restrict__ W2,
                         const float* __restrict__ b2, float* __restrict__ logits) {
    __shared__ double sb[256];
    int bn = blockIdx.x;
    int b = bn / 5, n = bn % 5;
    double s = 0.0;
    for (int k = threadIdx.x; k < 1024; k += 256)
        s += (double)T1[b * 1024 + k] * (double)W2[k * 5 + n];
    sb[threadIdx.x] = s; __syncthreads();
    for (int off = 128; off > 0; off >>= 1) {
        if (threadIdx.x < off) sb[threadIdx.x] += sb[threadIdx.x + off];
        __syncthreads();
    }
    if (threadIdx.x == 0) logits[b * 5 + n] = (float)(sb[0] + (double)b2[n]);
}

__global__ void sims_kernel(const float* __restrict__ logits, int* __restrict__ sims) {
    int b = threadIdx.x;
    if (b >= BATCH) return;
    float best = logits[b * 5 + 0]; int biv = 0;
    for (int i = 1; i < 5; i++) {
        float v = logits[b * 5 + i];
        if (v > best) { best = v; biv = i; }
    }
    const int opt[5] = {10, 25, 50, 75, 100};
    sims[b] = opt[biv];
}

// Per (t,b): JAX PARTITIONABLE threefry (byte-identical to rounds 5-11)
__global__ void gumbel_kernel(const float* __restrict__ fl,
                              int* __restrict__ idxj, int* __restrict__ vidx) {
    __shared__ float sv[256][3];
    __shared__ int   si[256][3];
    int blk = blockIdx.x;           // c = t*16+b
    int t = blk >> 4, b = blk & 15;
    uint32_t kk0, kk1;
    threefry(0u, 42u, 0u, (uint32_t)t, kk0, kk1);   // fold_in(key(42), t)
    int tid = threadIdx.x;
    float bv[3] = {-INFINITY, -INFINITY, -INFINITY};
    int   bi[3] = {0x7FFFFFFF, 0x7FFFFFFF, 0x7FFFFFFF};
    for (int s = tid; s < SEQ; s += 256) {
        uint32_t m = (uint32_t)(b * SEQ + s);
        uint32_t y0, y1;
        threefry(kk0, kk1, 0u, m, y0, y1);
        uint32_t bits = y0 ^ y1;
        float f = __uint_as_float((bits >> 9) | 0x3F800000u) - 1.0f;
        float u = fmaxf(1.17549435e-38f, f);
        float l1 = (float)log((double)u);
        float l2 = (float)log(-(double)l1);
        float g  = -l2;
        float val = fl[b * SEQ + s] + g;
        if (better(val, s, bv[2], bi[2])) {
            bv[2] = val; bi[2] = s;
            if (better(bv[2], bi[2], bv[1], bi[1])) {
                float tv = bv[1]; int ti = bi[1];
                bv[1] = bv[2]; bi[1] = bi[2]; bv[2] = tv; bi[2] = ti;
            }
            if (better(bv[1], bi[1], bv[0], bi[0])) {
                float tv = bv[0]; int ti = bi[0];
                bv[0] = bv[1]; bi[0] = bi[1]; bv[1] = tv; bi[1] = ti;
            }
        }
    }
    sv[tid][0] = bv[0]; sv[tid][1] = bv[1]; sv[tid][2] = bv[2];
    si[tid][0] = bi[0]; si[tid][1] = bi[1]; si[tid][2] = bi[2];
    __syncthreads();
    for (int off = 128; off > 0; off >>= 1) {
        if (tid < off) {
            float av[3] = {sv[tid][0], sv[tid][1], sv[tid][2]};
            int   ai[3] = {si[tid][0], si[tid][1], si[tid][2]};
            float cv[3] = {sv[tid + off][0], sv[tid + off][1], sv[tid + off][2]};
            int   ci[3] = {si[tid + off][0], si[tid + off][1], si[tid + off][2]};
            float rv[3]; int ri[3]; int pa = 0, pb = 0;
#pragma unroll
            for (int r = 0; r < 3; r++) {
                if (better(av[pa], ai[pa], cv[pb], ci[pb])) { rv[r] = av[pa]; ri[r] = ai[pa]; pa++; }
                else                                        { rv[r] = cv[pb]; ri[r] = ci[pb]; pb++; }
            }
            sv[tid][0] = rv[0]; sv[tid][1] = rv[1]; sv[tid][2] = rv[2];
            si[tid][0] = ri[0]; si[tid][1] = ri[1]; si[tid][2] = ri[2];
        }
        __syncthreads();
    }
    if (tid == 0) {
        idxj[0 * NCHAIN + blk] = b * SEQ + si[0][0];
        idxj[1 * NCHAIN + blk] = b * SEQ + si[0][1];
        idxj[2 * NCHAIN + blk] = b * SEQ + si[0][2];
        vidx[blk] = b;
    }
}

__global__ void meaninit_kernel(const float* __restrict__ rmean, float* __restrict__ mean_cur,
                                unsigned short* __restrict__ mc_bf) {
    int e = blockIdx.x * 256 + threadIdx.x;
    int c = e >> 10, hh = e & 1023;
    float v = rmean[(c & 15) * HDIM + hh];
    mean_cur[e] = v;
    mc_bf[e] = f2bf(v);
}

__global__ void meanupd_kernel(const float* __restrict__ NSj, const float* __restrict__ root,
                               const int* __restrict__ idx, float* __restrict__ mean_cur,
                               unsigned short* __restrict__ mc_bf) {
    int e = blockIdx.x * 256 + threadIdx.x;
    int c = e >> 10, hh = e & 1023;
    int r = idx[c];
    double m = (double)mean_cur[e] +
               ((double)NSj[e] - (double)root[(size_t)r * HDIM + hh]) * (1.0 / 1024.0);
    float v = (float)m;
    mean_cur[e] = v;
    mc_bf[e] = f2bf(v);
}

__global__ void valdot_kernel(const float* __restrict__ HV, const float* __restrict__ Wav2,
                              const float* __restrict__ bav2, float* __restrict__ w) {
    __shared__ double sb[256];
    int c = blockIdx.x, tid = threadIdx.x;
    double s = 0.0;
    for (int k = tid; k < HDIM; k += 256) s += (double)HV[(size_t)c * HDIM + k] * (double)Wav2[k];
    sb[tid] = s; __syncthreads();
    for (int off = 128; off > 0; off >>= 1) {
        if (tid < off) sb[tid] += sb[tid + off];
        __syncthreads();
    }
    if (tid == 0) {
        double v = sb[0] + (double)bav2[0];
        w[c] = (float)(1.0 / (1.0 + exp(-v)));
    }
}

__global__ void wsum_kernel(const float* __restrict__ w, const int* __restrict__ sims,
                            double* __restrict__ Wsum) {
    int b = threadIdx.x;
    if (b >= BATCH) return;
    int sb = sims[b];
    double s = 0.0;
    for (int t = 0; t < sb; t++) s += (double)w[t * BATCH + b];
    Wsum[b] = s;
}

__global__ void accinit_kernel(const float* __restrict__ root, const double* __restrict__ Wsum,
                               float* __restrict__ acc) {
    size_t e = (size_t)blockIdx.x * 256 + threadIdx.x;
    int b = (int)(e >> 20);
    acc[e] = (float)((1.0 + Wsum[b]) * (double)root[e]);
}

__global__ __launch_bounds__(256)
void corrections_atomic(const float* __restrict__ NS, const float* __restrict__ root,
                        const float* __restrict__ w, const int* __restrict__ sims,
                        const int* __restrict__ idxj, float* __restrict__ acc) {
    int blk = blockIdx.x;                // 0..4799
    int j = blk / NCHAIN, c = blk % NCHAIN;
    int b = c & 15, t = c >> 4;
    if (t >= sims[b]) return;
    float wv = w[c];
    int row = idxj[j * NCHAIN + c];
    const float* ns = NS + ((long)j * NCHAIN + c) * 1024;
    const float* rt = root + (long)row * 1024;
    float* ac = acc + (long)row * 1024;
    for (int h = threadIdx.x; h < 1024; h += 256)
        atomicAdd(&ac[h], wv * (ns[h] - rt[h]));
}

// ------------------------------- launch ------------------------------------
extern "C" void kernel_launch(void* const* d_in, const int* in_sizes, int n_in,
                              void* d_out, int out_size, void* d_ws, size_t ws_size,
                              hipStream_t stream) {
    (void)in_sizes; (void)n_in; (void)out_size; (void)ws_size;
    const float* root = (const float*)d_in[0];
    const int*   amask = (const int*)d_in[1];
    const float* Wsc1 = (const float*)d_in[2];  const float* bsc1 = (const float*)d_in[3];
    const float* Wsc2 = (const float*)d_in[4];  const float* bsc2 = (const float*)d_in[5];
    const float* Wp1  = (const float*)d_in[6];  const float* bp1  = (const float*)d_in[7];
    const float* Wp2  = (const float*)d_in[8];  const float* bp2  = (const float*)d_in[9];
    const float* Wt1  = (const float*)d_in[10]; const float* bt1  = (const float*)d_in[11];
    const float* Wt2  = (const float*)d_in[12]; const float* bt2  = (const float*)d_in[13];
    const float* Wav1 = (const float*)d_in[14]; const float* bav1 = (const float*)d_in[15];
    const float* Wav2 = (const float*)d_in[16]; const float* bav2 = (const float*)d_in[17];
    const float* Wg1  = (const float*)d_in[18]; const float* bg1  = (const float*)d_in[19];
    const float* Wg2  = (const float*)d_in[20]; const float* bg2  = (const float*)d_in[21];
    float* out = (float*)d_out;

    // ---- workspace carving (~123.6 MB; < round-10's proven 127.8 MB) ----
    char* p = (char*)d_ws;
    auto carve = [&](size_t nbytes) -> void* {
        void* r = (void*)p; p += (nbytes + 255) & ~(size_t)255; return r;
    };
    float*          mean_cur = (float*)carve((size_t)NCHAIN * HDIM * 4);
    unsigned short* H1bf     = (unsigned short*)carve((size_t)NCHAIN * HDIM * 2);
    float*          Hav      = (float*)carve((size_t)NCHAIN * HDIM * 4);
    float*          NS       = (float*)carve((size_t)3 * NCHAIN * HDIM * 4);
    unsigned short* h_bf     = (unsigned short*)mean_cur;  // step-9 alias (33.55MB<=36MB)
    unsigned short* WT3      = (unsigned short*)NS;        // policy weights: dead before NS written
    unsigned short* WTt1  = (unsigned short*)carve((size_t)1024 * 2048 * 2);
    unsigned short* WTt2  = (unsigned short*)carve((size_t)1024 * 1024 * 2);
    unsigned short* WTav1 = (unsigned short*)carve((size_t)1024 * 2048 * 2);
    unsigned short* WTg1  = (unsigned short*)carve((size_t)1024 * 2048 * 2);
    unsigned short* WTg2  = (unsigned short*)carve((size_t)1024 * 1024 * 2);
    float*  rmean  = (float*)carve(BATCH * HDIM * 4);
    float*  T1     = (float*)carve(BATCH * HDIM * 4);
    float*  logits = (float*)carve(128 * 4);
    float*  wp2m   = (float*)carve(1040 * 4);
    double* fl64   = (double*)carve((size_t)BATCH * SEQ * 8);
    float*  fl32   = (float*)carve(BATCH * SEQ * 4);
    float*  wbuf   = (float*)carve(NCHAIN * 4);
    double* Wsumd  = (double*)carve(64 * 8);
    int*    sims   = (int*)carve(64 * 4);
    int*    idxj   = (int*)carve(3 * NCHAIN * 4);
    int*    vidx   = (int*)carve(NCHAIN * 4);
    unsigned short* root_bf     = (unsigned short*)carve((size_t)BATCH * SEQ * HDIM * 2);
    unsigned short* acc_bf      = (unsigned short*)carve((size_t)BATCH * SEQ * HDIM * 2);
    unsigned short* root_lo     = acc_bf;   // policy (step 4) dead before acc_bf (step 8b)
    unsigned short* mean_cur_bf = (unsigned short*)carve((size_t)NCHAIN * HDIM * 2);
    unsigned short* rmean_bf    = (unsigned short*)carve(BATCH * HDIM * 2);

    const long NTOT8 = (long)BATCH * SEQ * HDIM / 8;
    const int  KBIG = 1 << 30, KMA = 0x7FFFFFFF;

    // 1) weight transposes (+ policy hi/lo triple-stack)
    transpose_bf16<<<dim3(2048 / 32, 1024 / 32), 256, 0, stream>>>(Wt1, WTt1, 2048, 1024);
    transpose_bf16<<<dim3(1024 / 32, 1024 / 32), 256, 0, stream>>>(Wt2, WTt2, 1024, 1024);
    transpose_bf16<<<dim3(2048 / 32, 1024 / 32), 256, 0, stream>>>(Wav1, WTav1, 2048, 1024);
    transpose_bf16<<<dim3(2048 / 32, 1024 / 32), 256, 0, stream>>>(Wg1, WTg1, 2048, 1024);
    transpose_bf16<<<dim3(1024 / 32, 1024 / 32), 256, 0, stream>>>(Wg2, WTg2, 1024, 1024);
    transpose_split3<<<dim3(32, 32), 256, 0, stream>>>(Wp1, WT3, 1024, 1024);
    // 1b) root -> bf16 hi+lo once (root_lo aliases acc_bf)
    cvt_split<<<2048, 256, 0, stream>>>(root, root_bf, root_lo, NTOT8);
    // 2) wp2 means, root mean
    wp2mean_kernel<<<1025, 256, 0, stream>>>(Wp2, bp2, wp2m);
    rootmean_kernel<<<dim3(BATCH, HDIM / 256), 256, 0, stream>>>(root, rmean, rmean_bf);
    // 3) controller (fp64) -> sims
    ctrl_fc1<<<64, 256, 0, stream>>>(root, Wsc1, bsc1, T1);
    ctrl_fc2<<<80, 256, 0, stream>>>(T1, Wsc2, bsc2, logits);
    sims_kernel<<<1, 64, 0, stream>>>(logits, sims);
    // 4) policy as pipelined K=3072 GEMM ([hi|hi|lo]) + fused fl epilogue
    hipMemsetAsync(fl64, 0, (size_t)BATCH * SEQ * 8, stream);
    gemm_bt<128, 1><<<dim3(8, 128), 512, 0, stream>>>(
        root_bf, 1024, nullptr, root_lo, 1024, nullptr, 2048, 1023,
        WT3, bp1, wp2m, fl64, nullptr, nullptr, nullptr, 1024,
        BATCH * SEQ, 1024, 3072, 0);
    flbuild_kernel<<<BATCH * SEQ / 256, 256, 0, stream>>>(fl64, wp2m, amask, fl32);
    // 5) gumbel top-3 (partitionable threefry, unchanged)
    gumbel_kernel<<<NCHAIN, 256, 0, stream>>>(fl32, idxj, vidx);
    // 6) transitions (TM=64, pipelined)
    meaninit_kernel<<<NCHAIN * HDIM / 256, 256, 0, stream>>>(rmean, mean_cur, mean_cur_bf);
    for (int j = 0; j < 3; j++) {
        gemm_bt<64, 0><<<dim3(8, 25), 512, 0, stream>>>(
            mean_cur_bf, 1024, nullptr, root_bf, 1024, idxj + j * NCHAIN, 1024, KMA,
            WTt1, bt1, nullptr, nullptr, nullptr, nullptr, H1bf, 1024,
            NCHAIN, 1024, 2048, 1);
        gemm_bt<64, 0><<<dim3(8, 25), 512, 0, stream>>>(
            H1bf, 1024, nullptr, nullptr, 0, nullptr, KBIG, KMA,
            WTt2, bt2, nullptr, nullptr, nullptr, NS + (size_t)j * NCHAIN * HDIM, nullptr,
            1024, NCHAIN, 1024, 1024, 0);
        meanupd_kernel<<<NCHAIN * HDIM / 256, 256, 0, stream>>>(
            NS + (size_t)j * NCHAIN * HDIM, root, idxj + j * NCHAIN, mean_cur, mean_cur_bf);
    }
    // 7) action value -> w -> Wsum
    gemm_bt<64, 0><<<dim3(8, 25), 512, 0, stream>>>(
        rmean_bf, 1024, vidx, mean_cur_bf, 1024, nullptr, 1024, KMA,
        WTav1, bav1, nullptr, nullptr, nullptr, Hav, nullptr, 1024,
        NCHAIN, 1024, 2048, 1);
    valdot_kernel<<<NCHAIN, 256, 0, stream>>>(Hav, Wav2, bav2, wbuf);
    wsum_kernel<<<1, 64, 0, stream>>>(wbuf, sims, Wsumd);
    // 8) acc (in d_out): init + parallel corrections + bf16 copy
    accinit_kernel<<<(BATCH * SEQ * HDIM) / 256, 256, 0, stream>>>(root, Wsumd, out);
    corrections_atomic<<<3 * NCHAIN, 256, 0, stream>>>(NS, root, wbuf, sims, idxj, out);
    cvt_split<<<2048, 256, 0, stream>>>(out, acc_bf, nullptr, NTOT8);
    // 9) aggregation (TM=128, pipelined)
    gemm_bt<128, 0><<<dim3(8, 128), 512, 0, stream>>>(
        root_bf, 1024, nullptr, acc_bf, 1024, nullptr, 1024, KMA,
        WTg1, bg1, nullptr, nullptr, nullptr, nullptr, h_bf, 1024,
        BATCH * SEQ, 1024, 2048, 1);
    gemm_bt<128, 0><<<dim3(8, 128), 512, 0, stream>>>(
        h_bf, 1024, nullptr, nullptr, 0, nullptr, KBIG, KMA,
        WTg2, bg2, nullptr, nullptr, root, out, nullptr, 1024,
        BATCH * SEQ, 1024, 1024, 0);
}

// Round 13
// 798.317 us; speedup vs baseline: 1.3956x; 1.0973x over previous
//
#include <hip/hip_runtime.h>
#include <hip/hip_bf16.h>
#include <cstdint>
#include <math.h>

// ---------------------------------------------------------------------------
// AdaptiveMCTSReasoner  B=16, S=1024, H=1024, MAX_SIMS=100, K_FOCUS=3
// Round 13: R12's pipelined dbuf GEMM with BK=32 (was 64). LDS 65KB -> 32.5KB
// => 4 blocks/CU x 8 waves = 32 waves/CU (full occupancy): stalled blocks
// hide behind 3 computing ones. 64B LDS rows make each wave's ds_read_b128
// cover 16 rows x all 4 chunks -> bank-uniform WITHOUT swizzle; staging is
// 1 linear gll/thread per operand. Everything else identical to R12 (passed).
// ---------------------------------------------------------------------------

#define SEQ 1024
#define BATCH 16
#define HDIM 1024
#define NSIM 100
#define NCHAIN (NSIM * BATCH)   // 1600
#define SHC (SEQ * HDIM)

typedef short bf16x8 __attribute__((ext_vector_type(8)));
typedef float f32x4 __attribute__((ext_vector_type(4)));
typedef float float4v __attribute__((ext_vector_type(4)));

__device__ __forceinline__ unsigned short f2bf(float f) {
    union { float f; uint32_t u; } c; c.f = f;
    uint32_t u = c.u;
    return (unsigned short)((u + 0x7FFFu + ((u >> 16) & 1u)) >> 16);   // RNE
}
__device__ __forceinline__ float bf2f(unsigned short h) {
    union { uint32_t u; float f; } c; c.u = ((uint32_t)h) << 16;
    return c.f;
}

__device__ __forceinline__ void gll16(const void* g, void* l) {
    __builtin_amdgcn_global_load_lds(
        (const __attribute__((address_space(1))) void*)g,
        (__attribute__((address_space(3))) void*)l, 16, 0, 0);
}

__device__ __forceinline__ float gelu32(float x) {
    return 0.5f * x * (1.0f + erff(x * 0.70710678f));
}

// XCD-aware bijective swizzle (requires nwg % 8 == 0; all our grids qualify)
__device__ __forceinline__ void swz_block(int& bx, int& by) {
    int gx = gridDim.x;
    int h = blockIdx.y * gx + blockIdx.x;
    int nwg = gx * gridDim.y;
    int l = (h & 7) * (nwg >> 3) + (h >> 3);
    bx = l % gx; by = l / gx;
}

// ------------------------------- threefry ----------------------------------
__device__ __forceinline__ uint32_t rotl32(uint32_t v, int r) {
    return (v << r) | (v >> (32 - r));
}

__device__ __forceinline__ void threefry(uint32_t k0, uint32_t k1,
                                         uint32_t c0, uint32_t c1,
                                         uint32_t& o0, uint32_t& o1) {
    uint32_t ks0 = k0, ks1 = k1, ks2 = k0 ^ k1 ^ 0x1BD11BDAu;
    uint32_t x0 = c0 + ks0, x1 = c1 + ks1;
#define TFR(r) { x0 += x1; x1 = rotl32(x1, r); x1 ^= x0; }
    TFR(13) TFR(15) TFR(26) TFR(6)   x0 += ks1; x1 += ks2 + 1u;
    TFR(17) TFR(29) TFR(16) TFR(24)  x0 += ks2; x1 += ks0 + 2u;
    TFR(13) TFR(15) TFR(26) TFR(6)   x0 += ks0; x1 += ks1 + 3u;
    TFR(17) TFR(29) TFR(16) TFR(24)  x0 += ks1; x1 += ks2 + 4u;
    TFR(13) TFR(15) TFR(26) TFR(6)   x0 += ks2; x1 += ks0 + 5u;
#undef TFR
    o0 = x0; o1 = x1;
}

__device__ __forceinline__ bool better(float va, int ia, float vb, int ib) {
    return (va > vb) || (va == vb && ia < ib);
}

// ----------------- weight transpose+convert: WT[n][k] = bf16(W[k][n]) ------
__global__ __launch_bounds__(256)
void transpose_bf16(const float* __restrict__ W, unsigned short* __restrict__ WT,
                    int K, int N) {
    __shared__ float t[32][33];
    int kb = blockIdx.x * 32, nb = blockIdx.y * 32;
    int tx = threadIdx.x & 31, ty4 = threadIdx.x >> 5;
#pragma unroll
    for (int p = 0; p < 4; ++p) {
        int ky = ty4 + p * 8;
        t[ky][tx] = W[(long)(kb + ky) * N + nb + tx];
    }
    __syncthreads();
#pragma unroll
    for (int p = 0; p < 4; ++p) {
        int ny = ty4 + p * 8;
        WT[(long)(nb + ny) * K + kb + tx] = f2bf(t[tx][ny]);
    }
}

// WT3[n][0:1024]=hi, [1024:2048]=lo, [2048:3072]=hi  (for policy bf16x3)
__global__ __launch_bounds__(256)
void transpose_split3(const float* __restrict__ W, unsigned short* __restrict__ WT3,
                      int K, int N) {
    __shared__ float t[32][33];
    int kb = blockIdx.x * 32, nb = blockIdx.y * 32;
    int tx = threadIdx.x & 31, ty4 = threadIdx.x >> 5;
#pragma unroll
    for (int p = 0; p < 4; ++p) {
        int ky = ty4 + p * 8;
        t[ky][tx] = W[(long)(kb + ky) * N + nb + tx];
    }
    __syncthreads();
#pragma unroll
    for (int p = 0; p < 4; ++p) {
        int ny = ty4 + p * 8;
        float w = t[tx][ny];
        unsigned short h = f2bf(w);
        unsigned short l = f2bf(w - bf2f(h));
        long base = (long)(nb + ny) * 3072;
        WT3[base + kb + tx] = h;
        WT3[base + 1024 + kb + tx] = l;
        WT3[base + 2048 + kb + tx] = h;
    }
}

// ---------- fp32 -> bf16 hi [+ optional lo split], bit-identical RNE --------
__global__ __launch_bounds__(256)
void cvt_split(const float* __restrict__ src, unsigned short* __restrict__ hi,
               unsigned short* __restrict__ lo, long n8) {
    long i = (long)blockIdx.x * 256 + threadIdx.x;
    long stride = (long)gridDim.x * 256;
    for (; i < n8; i += stride) {
        const float* s = src + i * 8;
        float4v v0 = *(const float4v*)s;
        float4v v1 = *(const float4v*)(s + 4);
        bf16x8 h, l;
#pragma unroll
        for (int e = 0; e < 4; ++e) {
            unsigned short h0 = f2bf(v0[e]);
            h[e] = (short)h0;
            unsigned short h1 = f2bf(v1[e]);
            h[e + 4] = (short)h1;
            if (lo) {
                l[e] = (short)f2bf(v0[e] - bf2f(h0));
                l[e + 4] = (short)f2bf(v1[e] - bf2f(h1));
            }
        }
        *(bf16x8*)&hi[i * 8] = h;
        if (lo) *(bf16x8*)&lo[i * 8] = l;
    }
}

// ------- pipelined GEMM (bf16 MFMA, B^T weights, dbuf, BK=32, 8 waves) -----
// TM = tile rows (128/64). 512 threads = 8 waves as 2x4; wave tile (TM/2)x32.
// BK=32 -> LDS 32.5KB -> 4 blocks/CU (32 waves/CU). Double-buffered, ONE
// barrier per K-step: barrier -> stage(next, buf^1) -> compute(buf). Linear
// LDS rows of 32 bf16 (64B): wave b128 reads cover 16 rows x 4 chunks ->
// bank-uniform, no swizzle. A: dual source (k<K1 -> Av1 with kb=k0&kmod1,
// else Av2), per-source row gathers. EPI=0: C/Cbf (+gelu,+Cadd). EPI=1:
// fused focus-logit epilogue.
template<int TM, int EPI>
__global__ __launch_bounds__(512)
void gemm_bt(const unsigned short* __restrict__ Av1, long lda1, const int* __restrict__ a1rows,
             const unsigned short* __restrict__ Av2, long lda2, const int* __restrict__ a2rows,
             int K1, int kmod1,
             const unsigned short* __restrict__ WT,
             const float* __restrict__ bias,
             const float* __restrict__ wp2m, double* __restrict__ fl64,
             const float* __restrict__ Cadd,
             float* __restrict__ C,
             unsigned short* __restrict__ Cbf,
             long ldc, int M, int N, int K, int doGelu) {
    constexpr int MT = TM / 32;          // row-frags per wave (wave rows = TM/2)
    constexpr int WROWS = TM / 2;
    constexpr int ASLOT = TM * 4;        // 16B slots in A tile (TM rows x 4 chunks)
    __shared__ unsigned short As[2][TM * 32];
    __shared__ unsigned short Bs[2][128 * 32];
    __shared__ int r1s[TM], r2s[TM];
    int tid = threadIdx.x;
    int bx, by; swz_block(bx, by);
    int row0 = by * TM, col0 = bx * 128;
    if (tid < TM) {
        int gm = row0 + tid; if (gm >= M) gm = M - 1;
        r1s[tid] = a1rows ? a1rows[gm] : gm;
        r2s[tid] = a2rows ? a2rows[gm] : gm;
    }
    int wid = tid >> 6, lane = tid & 63;
    int wr = wid >> 2, wc = wid & 3;          // 2 x 4 wave grid
    int llo = lane & 15, lhi = lane >> 4;
    f32x4 acc[MT][2];
#pragma unroll
    for (int i = 0; i < MT; i++)
#pragma unroll
        for (int j = 0; j < 2; j++) acc[i][j] = (f32x4){0.f, 0.f, 0.f, 0.f};
    __syncthreads();                               // r1s/r2s visible

    auto stage = [&](int k0, int b) {
        // B tile: 128 rows x 4 chunks = 512 slots = 512 threads
        {
            int r = tid >> 2, c = tid & 3;
            gll16(WT + (long)(col0 + r) * K + (k0 + (c << 3)),
                  (char*)Bs[b] + (tid << 4));
        }
        // A tile: TM rows x 4 chunks
        bool s1 = (k0 < K1);
        const unsigned short* Ab = s1 ? Av1 : Av2;
        const int* rsel = s1 ? r1s : r2s;
        long lda = s1 ? lda1 : lda2;
        int kb = s1 ? (k0 & kmod1) : (k0 - K1);
        if (ASLOT == 512 || tid < ASLOT) {
            int r = tid >> 2, c = tid & 3;
            gll16(Ab + (long)rsel[r] * lda + (kb + (c << 3)),
                  (char*)As[b] + (tid << 4));
        }
    };

    stage(0, 0);
    int nIt = K >> 5;
    for (int it = 0; it < nIt; ++it) {
        int cur = it & 1;
        __syncthreads();                 // drains gll into buf[cur]
        if (it + 1 < nIt) stage((it + 1) << 5, cur ^ 1);
        __builtin_amdgcn_sched_barrier(0);   // keep next-tile loads issued early
        char* AsB = (char*)As[cur];
        char* BsB = (char*)Bs[cur];
        bf16x8 af[MT], bfv[2];
#pragma unroll
        for (int mt = 0; mt < MT; ++mt) {
            int r = wr * WROWS + mt * 16 + llo;
            af[mt] = *(const bf16x8*)(AsB + (r << 6) + (lhi << 4));
        }
#pragma unroll
        for (int nt = 0; nt < 2; ++nt) {
            int r = wc * 32 + nt * 16 + llo;
            bfv[nt] = *(const bf16x8*)(BsB + (r << 6) + (lhi << 4));
        }
#pragma unroll
        for (int mt = 0; mt < MT; ++mt)
#pragma unroll
            for (int nt = 0; nt < 2; ++nt)
                acc[mt][nt] = __builtin_amdgcn_mfma_f32_16x16x32_bf16(
                    af[mt], bfv[nt], acc[mt][nt], 0, 0, 0);
    }
    // epilogue: C/D col=lane&15, row=(lane>>4)*4+reg  [m89-verified]
    if constexpr (EPI == 0) {
#pragma unroll
        for (int mt = 0; mt < MT; ++mt) {
#pragma unroll
            for (int nt = 0; nt < 2; ++nt) {
                int gn = col0 + wc * 32 + nt * 16 + llo;
#pragma unroll
                for (int r = 0; r < 4; ++r) {
                    int gm = row0 + wr * WROWS + mt * 16 + lhi * 4 + r;
                    if (gm >= M) continue;
                    float v = acc[mt][nt][r] + bias[gn];
                    if (doGelu) v = gelu32(v);
                    if (Cadd) v += Cadd[(long)gm * ldc + gn];
                    if (C)   C[(long)gm * ldc + gn] = v;
                    if (Cbf) Cbf[(long)gm * ldc + gn] = f2bf(v);
                }
            }
        }
    } else {
        // fused focus-logit: fl64[m] += sum_n gelu(x)*wp2m[n]
#pragma unroll
        for (int mt = 0; mt < MT; ++mt) {
            double part[4] = {0.0, 0.0, 0.0, 0.0};
#pragma unroll
            for (int nt = 0; nt < 2; ++nt) {
                int gn = col0 + wc * 32 + nt * 16 + llo;
                float b = bias[gn], wn = wp2m[gn];
#pragma unroll
                for (int r = 0; r < 4; ++r) {
                    float x = acc[mt][nt][r] + b;
                    part[r] += (double)gelu32(x) * (double)wn;
                }
            }
#pragma unroll
            for (int r = 0; r < 4; ++r) {
                double v = part[r];
                v += __shfl_xor(v, 1);
                v += __shfl_xor(v, 2);
                v += __shfl_xor(v, 4);
                v += __shfl_xor(v, 8);
                if (llo == 0)
                    atomicAdd(&fl64[row0 + wr * WROWS + mt * 16 + lhi * 4 + r], v);
            }
        }
    }
}

__global__ void flbuild_kernel(const double* __restrict__ fl64,
                               const float* __restrict__ wp2m,
                               const int* __restrict__ amask,
                               float* __restrict__ fl32) {
    int m = blockIdx.x * 256 + threadIdx.x;
    fl32[m] = (amask[m] == 0) ? -1e9f : (float)(fl64[m] + (double)wp2m[1024]);
}

// --------------------------- small kernels ---------------------------------
__global__ void wp2mean_kernel(const float* __restrict__ Wp2,
                               const float* __restrict__ bp2,
                               float* __restrict__ outv) {
    __shared__ double sb[256];
    int r = blockIdx.x, tid = threadIdx.x;
    const float* src = (r < 1024) ? (Wp2 + (size_t)r * 1024) : bp2;
    double s = 0.0;
    for (int k = tid; k < 1024; k += 256) s += (double)src[k];
    sb[tid] = s; __syncthreads();
    for (int off = 128; off > 0; off >>= 1) {
        if (tid < off) sb[tid] += sb[tid + off];
        __syncthreads();
    }
    if (tid == 0) outv[r] = (float)(sb[0] * (1.0 / 1024.0));
}

__global__ void rootmean_kernel(const float* __restrict__ root, float* __restrict__ rmean,
                                unsigned short* __restrict__ rmean_bf) {
    int b = blockIdx.x;
    int h = blockIdx.y * 256 + threadIdx.x;
    const float* base = root + (size_t)b * SHC + h;
    double s = 0.0;
    for (int ss = 0; ss < SEQ; ss++) s += (double)base[(size_t)ss * HDIM];
    float v = (float)(s * (1.0 / 1024.0));
    rmean[b * HDIM + h] = v;
    rmean_bf[b * HDIM + h] = f2bf(v);
}

__global__ __launch_bounds__(256)
void ctrl_fc1(const float* __restrict__ root, const float* __restrict__ W,
              const float* __restrict__ b1, float* __restrict__ T1) {
    __shared__ double red[16][17];
    int ni = threadIdx.x & 15, kt = threadIdx.x >> 4;
    int n = blockIdx.x * 16 + ni;
    double accb[16];
#pragma unroll
    for (int bb = 0; bb < 16; ++bb) accb[bb] = 0.0;
    for (int k = kt * 64; k < kt * 64 + 64; ++k) {
        double w = (double)W[(long)k * 1024 + n];
#pragma unroll
        for (int bb = 0; bb < 16; ++bb)
            accb[bb] = fma((double)root[(long)bb * SHC + k], w, accb[bb]);
    }
    for (int bb = 0; bb < 16; ++bb) {
        red[kt][ni] = accb[bb];
        __syncthreads();
        if (kt == 0) {
            double s = 0.0;
            for (int q = 0; q < 16; ++q) s += red[q][ni];
            double x = s + (double)b1[n];
            T1[bb * 1024 + n] = (float)(0.5 * x * (1.0 + erf(x * 0.70710678118654752440)));
        }
        __syncthreads();
    }
}

__global__ void ctrl_fc2(const float* __restrict__ T1, const float* __restrict__ W2,
                         const float* __restrict__ b2, float* __restrict__ logits) {
    __shared__ double sb[256];
    int bn = blockIdx.x;
    int b = bn / 5, n = bn % 5;
    double s = 0.0;
    for (int k = threadIdx.x; k < 1024; k += 256)
        s += (double)T1[b * 1024 + k] * (double)W2[k * 5 + n];
    sb[threadIdx.x] = s; __syncthreads();
    for (int off = 128; off > 0; off >>= 1) {
        if (threadIdx.x < off) sb[threadIdx.x] += sb[threadIdx.x + off];
        __syncthreads();
    }
    if (threadIdx.x == 0) logits[b * 5 + n] = (float)(sb[0] + (double)b2[n]);
}

__global__ void sims_kernel(const float* __restrict__ logits, int* __restrict__ sims) {
    int b = threadIdx.x;
    if (b >= BATCH) return;
    float best = logits[b * 5 + 0]; int biv = 0;
    for (int i = 1; i < 5; i++) {
        float v = logits[b * 5 + i];
        if (v > best) { best = v; biv = i; }
    }
    const int opt[5] = {10, 25, 50, 75, 100};
    sims[b] = opt[biv];
}

// Per (t,b): JAX PARTITIONABLE threefry (byte-identical to rounds 5-12)
__global__ void gumbel_kernel(const float* __restrict__ fl,
                              int* __restrict__ idxj, int* __restrict__ vidx) {
    __shared__ float sv[256][3];
    __shared__ int   si[256][3];
    int blk = blockIdx.x;           // c = t*16+b
    int t = blk >> 4, b = blk & 15;
    uint32_t kk0, kk1;
    threefry(0u, 42u, 0u, (uint32_t)t, kk0, kk1);   // fold_in(key(42), t)
    int tid = threadIdx.x;
    float bv[3] = {-INFINITY, -INFINITY, -INFINITY};
    int   bi[3] = {0x7FFFFFFF, 0x7FFFFFFF, 0x7FFFFFFF};
    for (int s = tid; s < SEQ; s += 256) {
        uint32_t m = (uint32_t)(b * SEQ + s);
        uint32_t y0, y1;
        threefry(kk0, kk1, 0u, m, y0, y1);
        uint32_t bits = y0 ^ y1;
        float f = __uint_as_float((bits >> 9) | 0x3F800000u) - 1.0f;
        float u = fmaxf(1.17549435e-38f, f);
        float l1 = (float)log((double)u);
        float l2 = (float)log(-(double)l1);
        float g  = -l2;
        float val = fl[b * SEQ + s] + g;
        if (better(val, s, bv[2], bi[2])) {
            bv[2] = val; bi[2] = s;
            if (better(bv[2], bi[2], bv[1], bi[1])) {
                float tv = bv[1]; int ti = bi[1];
                bv[1] = bv[2]; bi[1] = bi[2]; bv[2] = tv; bi[2] = ti;
            }
            if (better(bv[1], bi[1], bv[0], bi[0])) {
                float tv = bv[0]; int ti = bi[0];
                bv[0] = bv[1]; bi[0] = bi[1]; bv[1] = tv; bi[1] = ti;
            }
        }
    }
    sv[tid][0] = bv[0]; sv[tid][1] = bv[1]; sv[tid][2] = bv[2];
    si[tid][0] = bi[0]; si[tid][1] = bi[1]; si[tid][2] = bi[2];
    __syncthreads();
    for (int off = 128; off > 0; off >>= 1) {
        if (tid < off) {
            float av[3] = {sv[tid][0], sv[tid][1], sv[tid][2]};
            int   ai[3] = {si[tid][0], si[tid][1], si[tid][2]};
            float cv[3] = {sv[tid + off][0], sv[tid + off][1], sv[tid + off][2]};
            int   ci[3] = {si[tid + off][0], si[tid + off][1], si[tid + off][2]};
            float rv[3]; int ri[3]; int pa = 0, pb = 0;
#pragma unroll
            for (int r = 0; r < 3; r++) {
                if (better(av[pa], ai[pa], cv[pb], ci[pb])) { rv[r] = av[pa]; ri[r] = ai[pa]; pa++; }
                else                                        { rv[r] = cv[pb]; ri[r] = ci[pb]; pb++; }
            }
            sv[tid][0] = rv[0]; sv[tid][1] = rv[1]; sv[tid][2] = rv[2];
            si[tid][0] = ri[0]; si[tid][1] = ri[1]; si[tid][2] = ri[2];
        }
        __syncthreads();
    }
    if (tid == 0) {
        idxj[0 * NCHAIN + blk] = b * SEQ + si[0][0];
        idxj[1 * NCHAIN + blk] = b * SEQ + si[0][1];
        idxj[2 * NCHAIN + blk] = b * SEQ + si[0][2];
        vidx[blk] = b;
    }
}

__global__ void meaninit_kernel(const float* __restrict__ rmean, float* __restrict__ mean_cur,
                                unsigned short* __restrict__ mc_bf) {
    int e = blockIdx.x * 256 + threadIdx.x;
    int c = e >> 10, hh = e & 1023;
    float v = rmean[(c & 15) * HDIM + hh];
    mean_cur[e] = v;
    mc_bf[e] = f2bf(v);
}

__global__ void meanupd_kernel(const float* __restrict__ NSj, const float* __restrict__ root,
                               const int* __restrict__ idx, float* __restrict__ mean_cur,
                               unsigned short* __restrict__ mc_bf) {
    int e = blockIdx.x * 256 + threadIdx.x;
    int c = e >> 10, hh = e & 1023;
    int r = idx[c];
    double m = (double)mean_cur[e] +
               ((double)NSj[e] - (double)root[(size_t)r * HDIM + hh]) * (1.0 / 1024.0);
    float v = (float)m;
    mean_cur[e] = v;
    mc_bf[e] = f2bf(v);
}

__global__ void valdot_kernel(const float* __restrict__ HV, const float* __restrict__ Wav2,
                              const float* __restrict__ bav2, float* __restrict__ w) {
    __shared__ double sb[256];
    int c = blockIdx.x, tid = threadIdx.x;
    double s = 0.0;
    for (int k = tid; k < HDIM; k += 256) s += (double)HV[(size_t)c * HDIM + k] * (double)Wav2[k];
    sb[tid] = s; __syncthreads();
    for (int off = 128; off > 0; off >>= 1) {
        if (tid < off) sb[tid] += sb[tid + off];
        __syncthreads();
    }
    if (tid == 0) {
        double v = sb[0] + (double)bav2[0];
        w[c] = (float)(1.0 / (1.0 + exp(-v)));
    }
}

__global__ void wsum_kernel(const float* __restrict__ w, const int* __restrict__ sims,
                            double* __restrict__ Wsum) {
    int b = threadIdx.x;
    if (b >= BATCH) return;
    int sb = sims[b];
    double s = 0.0;
    for (int t = 0; t < sb; t++) s += (double)w[t * BATCH + b];
    Wsum[b] = s;
}

__global__ void accinit_kernel(const float* __restrict__ root, const double* __restrict__ Wsum,
                               float* __restrict__ acc) {
    size_t e = (size_t)blockIdx.x * 256 + threadIdx.x;
    int b = (int)(e >> 20);
    acc[e] = (float)((1.0 + Wsum[b]) * (double)root[e]);
}

__global__ __launch_bounds__(256)
void corrections_atomic(const float* __restrict__ NS, const float* __restrict__ root,
                        const float* __restrict__ w, const int* __restrict__ sims,
                        const int* __restrict__ idxj, float* __restrict__ acc) {
    int blk = blockIdx.x;                // 0..4799
    int j = blk / NCHAIN, c = blk % NCHAIN;
    int b = c & 15, t = c >> 4;
    if (t >= sims[b]) return;
    float wv = w[c];
    int row = idxj[j * NCHAIN + c];
    const float* ns = NS + ((long)j * NCHAIN + c) * 1024;
    const float* rt = root + (long)row * 1024;
    float* ac = acc + (long)row * 1024;
    for (int h = threadIdx.x; h < 1024; h += 256)
        atomicAdd(&ac[h], wv * (ns[h] - rt[h]));
}

// ------------------------------- launch ------------------------------------
extern "C" void kernel_launch(void* const* d_in, const int* in_sizes, int n_in,
                              void* d_out, int out_size, void* d_ws, size_t ws_size,
                              hipStream_t stream) {
    (void)in_sizes; (void)n_in; (void)out_size; (void)ws_size;
    const float* root = (const float*)d_in[0];
    const int*   amask = (const int*)d_in[1];
    const float* Wsc1 = (const float*)d_in[2];  const float* bsc1 = (const float*)d_in[3];
    const float* Wsc2 = (const float*)d_in[4];  const float* bsc2 = (const float*)d_in[5];
    const float* Wp1  = (const float*)d_in[6];  const float* bp1  = (const float*)d_in[7];
    const float* Wp2  = (const float*)d_in[8];  const float* bp2  = (const float*)d_in[9];
    const float* Wt1  = (const float*)d_in[10]; const float* bt1  = (const float*)d_in[11];
    const float* Wt2  = (const float*)d_in[12]; const float* bt2  = (const float*)d_in[13];
    const float* Wav1 = (const float*)d_in[14]; const float* bav1 = (const float*)d_in[15];
    const float* Wav2 = (const float*)d_in[16]; const float* bav2 = (const float*)d_in[17];
    const float* Wg1  = (const float*)d_in[18]; const float* bg1  = (const float*)d_in[19];
    const float* Wg2  = (const float*)d_in[20]; const float* bg2  = (const float*)d_in[21];
    float* out = (float*)d_out;

    // ---- workspace carving (~123.6 MB; < round-10's proven 127.8 MB) ----
    char* p = (char*)d_ws;
    auto carve = [&](size_t nbytes) -> void* {
        void* r = (void*)p; p += (nbytes + 255) & ~(size_t)255; return r;
    };
    float*          mean_cur = (float*)carve((size_t)NCHAIN * HDIM * 4);
    unsigned short* H1bf     = (unsigned short*)carve((size_t)NCHAIN * HDIM * 2);
    float*          Hav      = (float*)carve((size_t)NCHAIN * HDIM * 4);
    float*          NS       = (float*)carve((size_t)3 * NCHAIN * HDIM * 4);
    unsigned short* h_bf     = (unsigned short*)mean_cur;  // step-9 alias (33.55MB<=36MB)
    unsigned short* WT3      = (unsigned short*)NS;        // policy weights: dead before NS written
    unsigned short* WTt1  = (unsigned short*)carve((size_t)1024 * 2048 * 2);
    unsigned short* WTt2  = (unsigned short*)carve((size_t)1024 * 1024 * 2);
    unsigned short* WTav1 = (unsigned short*)carve((size_t)1024 * 2048 * 2);
    unsigned short* WTg1  = (unsigned short*)carve((size_t)1024 * 2048 * 2);
    unsigned short* WTg2  = (unsigned short*)carve((size_t)1024 * 1024 * 2);
    float*  rmean  = (float*)carve(BATCH * HDIM * 4);
    float*  T1     = (float*)carve(BATCH * HDIM * 4);
    float*  logits = (float*)carve(128 * 4);
    float*  wp2m   = (float*)carve(1040 * 4);
    double* fl64   = (double*)carve((size_t)BATCH * SEQ * 8);
    float*  fl32   = (float*)carve(BATCH * SEQ * 4);
    float*  wbuf   = (float*)carve(NCHAIN * 4);
    double* Wsumd  = (double*)carve(64 * 8);
    int*    sims   = (int*)carve(64 * 4);
    int*    idxj   = (int*)carve(3 * NCHAIN * 4);
    int*    vidx   = (int*)carve(NCHAIN * 4);
    unsigned short* root_bf     = (unsigned short*)carve((size_t)BATCH * SEQ * HDIM * 2);
    unsigned short* acc_bf      = (unsigned short*)carve((size_t)BATCH * SEQ * HDIM * 2);
    unsigned short* root_lo     = acc_bf;   // policy (step 4) dead before acc_bf (step 8b)
    unsigned short* mean_cur_bf = (unsigned short*)carve((size_t)NCHAIN * HDIM * 2);
    unsigned short* rmean_bf    = (unsigned short*)carve(BATCH * HDIM * 2);

    const long NTOT8 = (long)BATCH * SEQ * HDIM / 8;
    const int  KBIG = 1 << 30, KMA = 0x7FFFFFFF;

    // 1) weight transposes (+ policy hi/lo triple-stack)
    transpose_bf16<<<dim3(2048 / 32, 1024 / 32), 256, 0, stream>>>(Wt1, WTt1, 2048, 1024);
    transpose_bf16<<<dim3(1024 / 32, 1024 / 32), 256, 0, stream>>>(Wt2, WTt2, 1024, 1024);
    transpose_bf16<<<dim3(2048 / 32, 1024 / 32), 256, 0, stream>>>(Wav1, WTav1, 2048, 1024);
    transpose_bf16<<<dim3(2048 / 32, 1024 / 32), 256, 0, stream>>>(Wg1, WTg1, 2048, 1024);
    transpose_bf16<<<dim3(1024 / 32, 1024 / 32), 256, 0, stream>>>(Wg2, WTg2, 1024, 1024);
    transpose_split3<<<dim3(32, 32), 256, 0, stream>>>(Wp1, WT3, 1024, 1024);
    // 1b) root -> bf16 hi+lo once (root_lo aliases acc_bf)
    cvt_split<<<2048, 256, 0, stream>>>(root, root_bf, root_lo, NTOT8);
    // 2) wp2 means, root mean
    wp2mean_kernel<<<1025, 256, 0, stream>>>(Wp2, bp2, wp2m);
    rootmean_kernel<<<dim3(BATCH, HDIM / 256), 256, 0, stream>>>(root, rmean, rmean_bf);
    // 3) controller (fp64) -> sims
    ctrl_fc1<<<64, 256, 0, stream>>>(root, Wsc1, bsc1, T1);
    ctrl_fc2<<<80, 256, 0, stream>>>(T1, Wsc2, bsc2, logits);
    sims_kernel<<<1, 64, 0, stream>>>(logits, sims);
    // 4) policy as pipelined K=3072 GEMM ([hi|hi|lo]) + fused fl epilogue
    hipMemsetAsync(fl64, 0, (size_t)BATCH * SEQ * 8, stream);
    gemm_bt<128, 1><<<dim3(8, 128), 512, 0, stream>>>(
        root_bf, 1024, nullptr, root_lo, 1024, nullptr, 2048, 1023,
        WT3, bp1, wp2m, fl64, nullptr, nullptr, nullptr, 1024,
        BATCH * SEQ, 1024, 3072, 0);
    flbuild_kernel<<<BATCH * SEQ / 256, 256, 0, stream>>>(fl64, wp2m, amask, fl32);
    // 5) gumbel top-3 (partitionable threefry, unchanged)
    gumbel_kernel<<<NCHAIN, 256, 0, stream>>>(fl32, idxj, vidx);
    // 6) transitions (TM=64, pipelined)
    meaninit_kernel<<<NCHAIN * HDIM / 256, 256, 0, stream>>>(rmean, mean_cur, mean_cur_bf);
    for (int j = 0; j < 3; j++) {
        gemm_bt<64, 0><<<dim3(8, 25), 512, 0, stream>>>(
            mean_cur_bf, 1024, nullptr, root_bf, 1024, idxj + j * NCHAIN, 1024, KMA,
            WTt1, bt1, nullptr, nullptr, nullptr, nullptr, H1bf, 1024,
            NCHAIN, 1024, 2048, 1);
        gemm_bt<64, 0><<<dim3(8, 25), 512, 0, stream>>>(
            H1bf, 1024, nullptr, nullptr, 0, nullptr, KBIG, KMA,
            WTt2, bt2, nullptr, nullptr, nullptr, NS + (size_t)j * NCHAIN * HDIM, nullptr,
            1024, NCHAIN, 1024, 1024, 0);
        meanupd_kernel<<<NCHAIN * HDIM / 256, 256, 0, stream>>>(
            NS + (size_t)j * NCHAIN * HDIM, root, idxj + j * NCHAIN, mean_cur, mean_cur_bf);
    }
    // 7) action value -> w -> Wsum
    gemm_bt<64, 0><<<dim3(8, 25), 512, 0, stream>>>(
        rmean_bf, 1024, vidx, mean_cur_bf, 1024, nullptr, 1024, KMA,
        WTav1, bav1, nullptr, nullptr, nullptr, Hav, nullptr, 1024,
        NCHAIN, 1024, 2048, 1);
    valdot_kernel<<<NCHAIN, 256, 0, stream>>>(Hav, Wav2, bav2, wbuf);
    wsum_kernel<<<1, 64, 0, stream>>>(wbuf, sims, Wsumd);
    // 8) acc (in d_out): init + parallel corrections + bf16 copy
    accinit_kernel<<<(BATCH * SEQ * HDIM) / 256, 256, 0, stream>>>(root, Wsumd, out);
    corrections_atomic<<<3 * NCHAIN, 256, 0, stream>>>(NS, root, wbuf, sims, idxj, out);
    cvt_split<<<2048, 256, 0, stream>>>(out, acc_bf, nullptr, NTOT8);
    // 9) aggregation (TM=128, pipelined)
    gemm_bt<128, 0><<<dim3(8, 128), 512, 0, stream>>>(
        root_bf, 1024, nullptr, acc_bf, 1024, nullptr, 1024, KMA,
        WTg1, bg1, nullptr, nullptr, nullptr, nullptr, h_bf, 1024,
        BATCH * SEQ, 1024, 2048, 1);
    gemm_bt<128, 0><<<dim3(8, 128), 512, 0, stream>>>(
        h_bf, 1024, nullptr, nullptr, 0, nullptr, KBIG, KMA,
        WTg2, bg2, nullptr, nullptr, root, out, nullptr, 1024,
        BATCH * SEQ, 1024, 1024, 0);
}

// Round 14
// 790.779 us; speedup vs baseline: 1.4089x; 1.0095x over previous
//
#include <hip/hip_runtime.h>
#include <hip/hip_bf16.h>
#include <cstdint>
#include <math.h>

// ---------------------------------------------------------------------------
// AdaptiveMCTSReasoner  B=16, S=1024, H=1024, MAX_SIMS=100, K_FOCUS=3
// Round 14: R13 + BK=32 LDS XOR-swizzle. R13's "bank-uniform" claim was wrong
// (1.9e7 conflicts: 64B rows -> fixed-lhi group 8-way). Fix: chunk ^= (r>>1)&3
// applied BOTH sides (inverse-swizzled gll source + swizzled ds_read), so any
// 8 consecutive rows tile all 32 banks once (same property as the proven
// BK=64 c^(r&7) scheme that measured 0 conflicts). Bytes identical -> absmax
// unchanged. Everything else identical to R13 (passed, 798us).
// ---------------------------------------------------------------------------

#define SEQ 1024
#define BATCH 16
#define HDIM 1024
#define NSIM 100
#define NCHAIN (NSIM * BATCH)   // 1600
#define SHC (SEQ * HDIM)

typedef short bf16x8 __attribute__((ext_vector_type(8)));
typedef float f32x4 __attribute__((ext_vector_type(4)));
typedef float float4v __attribute__((ext_vector_type(4)));

__device__ __forceinline__ unsigned short f2bf(float f) {
    union { float f; uint32_t u; } c; c.f = f;
    uint32_t u = c.u;
    return (unsigned short)((u + 0x7FFFu + ((u >> 16) & 1u)) >> 16);   // RNE
}
__device__ __forceinline__ float bf2f(unsigned short h) {
    union { uint32_t u; float f; } c; c.u = ((uint32_t)h) << 16;
    return c.f;
}

__device__ __forceinline__ void gll16(const void* g, void* l) {
    __builtin_amdgcn_global_load_lds(
        (const __attribute__((address_space(1))) void*)g,
        (__attribute__((address_space(3))) void*)l, 16, 0, 0);
}

__device__ __forceinline__ float gelu32(float x) {
    return 0.5f * x * (1.0f + erff(x * 0.70710678f));
}

// XCD-aware bijective swizzle (requires nwg % 8 == 0; all our grids qualify)
__device__ __forceinline__ void swz_block(int& bx, int& by) {
    int gx = gridDim.x;
    int h = blockIdx.y * gx + blockIdx.x;
    int nwg = gx * gridDim.y;
    int l = (h & 7) * (nwg >> 3) + (h >> 3);
    bx = l % gx; by = l / gx;
}

// ------------------------------- threefry ----------------------------------
__device__ __forceinline__ uint32_t rotl32(uint32_t v, int r) {
    return (v << r) | (v >> (32 - r));
}

__device__ __forceinline__ void threefry(uint32_t k0, uint32_t k1,
                                         uint32_t c0, uint32_t c1,
                                         uint32_t& o0, uint32_t& o1) {
    uint32_t ks0 = k0, ks1 = k1, ks2 = k0 ^ k1 ^ 0x1BD11BDAu;
    uint32_t x0 = c0 + ks0, x1 = c1 + ks1;
#define TFR(r) { x0 += x1; x1 = rotl32(x1, r); x1 ^= x0; }
    TFR(13) TFR(15) TFR(26) TFR(6)   x0 += ks1; x1 += ks2 + 1u;
    TFR(17) TFR(29) TFR(16) TFR(24)  x0 += ks2; x1 += ks0 + 2u;
    TFR(13) TFR(15) TFR(26) TFR(6)   x0 += ks0; x1 += ks1 + 3u;
    TFR(17) TFR(29) TFR(16) TFR(24)  x0 += ks1; x1 += ks2 + 4u;
    TFR(13) TFR(15) TFR(26) TFR(6)   x0 += ks2; x1 += ks0 + 5u;
#undef TFR
    o0 = x0; o1 = x1;
}

__device__ __forceinline__ bool better(float va, int ia, float vb, int ib) {
    return (va > vb) || (va == vb && ia < ib);
}

// ----------------- weight transpose+convert: WT[n][k] = bf16(W[k][n]) ------
__global__ __launch_bounds__(256)
void transpose_bf16(const float* __restrict__ W, unsigned short* __restrict__ WT,
                    int K, int N) {
    __shared__ float t[32][33];
    int kb = blockIdx.x * 32, nb = blockIdx.y * 32;
    int tx = threadIdx.x & 31, ty4 = threadIdx.x >> 5;
#pragma unroll
    for (int p = 0; p < 4; ++p) {
        int ky = ty4 + p * 8;
        t[ky][tx] = W[(long)(kb + ky) * N + nb + tx];
    }
    __syncthreads();
#pragma unroll
    for (int p = 0; p < 4; ++p) {
        int ny = ty4 + p * 8;
        WT[(long)(nb + ny) * K + kb + tx] = f2bf(t[tx][ny]);
    }
}

// WT3[n][0:1024]=hi, [1024:2048]=lo, [2048:3072]=hi  (for policy bf16x3)
__global__ __launch_bounds__(256)
void transpose_split3(const float* __restrict__ W, unsigned short* __restrict__ WT3,
                      int K, int N) {
    __shared__ float t[32][33];
    int kb = blockIdx.x * 32, nb = blockIdx.y * 32;
    int tx = threadIdx.x & 31, ty4 = threadIdx.x >> 5;
#pragma unroll
    for (int p = 0; p < 4; ++p) {
        int ky = ty4 + p * 8;
        t[ky][tx] = W[(long)(kb + ky) * N + nb + tx];
    }
    __syncthreads();
#pragma unroll
    for (int p = 0; p < 4; ++p) {
        int ny = ty4 + p * 8;
        float w = t[tx][ny];
        unsigned short h = f2bf(w);
        unsigned short l = f2bf(w - bf2f(h));
        long base = (long)(nb + ny) * 3072;
        WT3[base + kb + tx] = h;
        WT3[base + 1024 + kb + tx] = l;
        WT3[base + 2048 + kb + tx] = h;
    }
}

// ---------- fp32 -> bf16 hi [+ optional lo split], bit-identical RNE --------
__global__ __launch_bounds__(256)
void cvt_split(const float* __restrict__ src, unsigned short* __restrict__ hi,
               unsigned short* __restrict__ lo, long n8) {
    long i = (long)blockIdx.x * 256 + threadIdx.x;
    long stride = (long)gridDim.x * 256;
    for (; i < n8; i += stride) {
        const float* s = src + i * 8;
        float4v v0 = *(const float4v*)s;
        float4v v1 = *(const float4v*)(s + 4);
        bf16x8 h, l;
#pragma unroll
        for (int e = 0; e < 4; ++e) {
            unsigned short h0 = f2bf(v0[e]);
            h[e] = (short)h0;
            unsigned short h1 = f2bf(v1[e]);
            h[e + 4] = (short)h1;
            if (lo) {
                l[e] = (short)f2bf(v0[e] - bf2f(h0));
                l[e + 4] = (short)f2bf(v1[e] - bf2f(h1));
            }
        }
        *(bf16x8*)&hi[i * 8] = h;
        if (lo) *(bf16x8*)&lo[i * 8] = l;
    }
}

// -- pipelined GEMM (bf16 MFMA, B^T weights, dbuf, BK=32, 8 waves, swizzled) --
// TM = tile rows (128/64). 512 threads = 8 waves as 2x4; wave tile (TM/2)x32.
// BK=32 -> LDS 32.5KB -> 4 blocks/CU (32 waves/CU). Double-buffered, ONE
// barrier per K-step. LDS chunk swizzle: physical_chunk = chunk ^ ((row>>1)&3)
// -> any 8 consecutive rows tile all 32 banks once (conflict-free b128 reads).
// Applied as inverse-swizzled gll SOURCE + swizzled ds_read (G21 involution).
// A: dual source (k<K1 -> Av1 with kb=k0&kmod1, else Av2), per-source row
// gathers. EPI=0: C/Cbf (+gelu,+Cadd). EPI=1: fused focus-logit epilogue.
template<int TM, int EPI>
__global__ __launch_bounds__(512)
void gemm_bt(const unsigned short* __restrict__ Av1, long lda1, const int* __restrict__ a1rows,
             const unsigned short* __restrict__ Av2, long lda2, const int* __restrict__ a2rows,
             int K1, int kmod1,
             const unsigned short* __restrict__ WT,
             const float* __restrict__ bias,
             const float* __restrict__ wp2m, double* __restrict__ fl64,
             const float* __restrict__ Cadd,
             float* __restrict__ C,
             unsigned short* __restrict__ Cbf,
             long ldc, int M, int N, int K, int doGelu) {
    constexpr int MT = TM / 32;          // row-frags per wave (wave rows = TM/2)
    constexpr int WROWS = TM / 2;
    constexpr int ASLOT = TM * 4;        // 16B slots in A tile (TM rows x 4 chunks)
    __shared__ unsigned short As[2][TM * 32];
    __shared__ unsigned short Bs[2][128 * 32];
    __shared__ int r1s[TM], r2s[TM];
    int tid = threadIdx.x;
    int bx, by; swz_block(bx, by);
    int row0 = by * TM, col0 = bx * 128;
    if (tid < TM) {
        int gm = row0 + tid; if (gm >= M) gm = M - 1;
        r1s[tid] = a1rows ? a1rows[gm] : gm;
        r2s[tid] = a2rows ? a2rows[gm] : gm;
    }
    int wid = tid >> 6, lane = tid & 63;
    int wr = wid >> 2, wc = wid & 3;          // 2 x 4 wave grid
    int llo = lane & 15, lhi = lane >> 4;
    f32x4 acc[MT][2];
#pragma unroll
    for (int i = 0; i < MT; i++)
#pragma unroll
        for (int j = 0; j < 2; j++) acc[i][j] = (f32x4){0.f, 0.f, 0.f, 0.f};
    __syncthreads();                               // r1s/r2s visible

    auto stage = [&](int k0, int b) {
        // B tile: 128 rows x 4 chunks = 512 slots; source chunk inverse-swizzled
        {
            int r = tid >> 2, cs = tid & 3, c = cs ^ ((r >> 1) & 3);
            gll16(WT + (long)(col0 + r) * K + (k0 + (c << 3)),
                  (char*)Bs[b] + (tid << 4));
        }
        // A tile: TM rows x 4 chunks
        bool s1 = (k0 < K1);
        const unsigned short* Ab = s1 ? Av1 : Av2;
        const int* rsel = s1 ? r1s : r2s;
        long lda = s1 ? lda1 : lda2;
        int kb = s1 ? (k0 & kmod1) : (k0 - K1);
        if (ASLOT == 512 || tid < ASLOT) {
            int r = tid >> 2, cs = tid & 3, c = cs ^ ((r >> 1) & 3);
            gll16(Ab + (long)rsel[r] * lda + (kb + (c << 3)),
                  (char*)As[b] + (tid << 4));
        }
    };

    stage(0, 0);
    int nIt = K >> 5;
    for (int it = 0; it < nIt; ++it) {
        int cur = it & 1;
        __syncthreads();                 // drains gll into buf[cur]
        if (it + 1 < nIt) stage((it + 1) << 5, cur ^ 1);
        __builtin_amdgcn_sched_barrier(0);   // keep next-tile loads issued early
        char* AsB = (char*)As[cur];
        char* BsB = (char*)Bs[cur];
        bf16x8 af[MT], bfv[2];
#pragma unroll
        for (int mt = 0; mt < MT; ++mt) {
            int r = wr * WROWS + mt * 16 + llo;
            int pc = lhi ^ ((r >> 1) & 3);
            af[mt] = *(const bf16x8*)(AsB + (r << 6) + (pc << 4));
        }
#pragma unroll
        for (int nt = 0; nt < 2; ++nt) {
            int r = wc * 32 + nt * 16 + llo;
            int pc = lhi ^ ((r >> 1) & 3);
            bfv[nt] = *(const bf16x8*)(BsB + (r << 6) + (pc << 4));
        }
#pragma unroll
        for (int mt = 0; mt < MT; ++mt)
#pragma unroll
            for (int nt = 0; nt < 2; ++nt)
                acc[mt][nt] = __builtin_amdgcn_mfma_f32_16x16x32_bf16(
                    af[mt], bfv[nt], acc[mt][nt], 0, 0, 0);
    }
    // epilogue: C/D col=lane&15, row=(lane>>4)*4+reg  [m89-verified]
    if constexpr (EPI == 0) {
#pragma unroll
        for (int mt = 0; mt < MT; ++mt) {
#pragma unroll
            for (int nt = 0; nt < 2; ++nt) {
                int gn = col0 + wc * 32 + nt * 16 + llo;
#pragma unroll
                for (int r = 0; r < 4; ++r) {
                    int gm = row0 + wr * WROWS + mt * 16 + lhi * 4 + r;
                    if (gm >= M) continue;
                    float v = acc[mt][nt][r] + bias[gn];
                    if (doGelu) v = gelu32(v);
                    if (Cadd) v += Cadd[(long)gm * ldc + gn];
                    if (C)   C[(long)gm * ldc + gn] = v;
                    if (Cbf) Cbf[(long)gm * ldc + gn] = f2bf(v);
                }
            }
        }
    } else {
        // fused focus-logit: fl64[m] += sum_n gelu(x)*wp2m[n]
#pragma unroll
        for (int mt = 0; mt < MT; ++mt) {
            double part[4] = {0.0, 0.0, 0.0, 0.0};
#pragma unroll
            for (int nt = 0; nt < 2; ++nt) {
                int gn = col0 + wc * 32 + nt * 16 + llo;
                float b = bias[gn], wn = wp2m[gn];
#pragma unroll
                for (int r = 0; r < 4; ++r) {
                    float x = acc[mt][nt][r] + b;
                    part[r] += (double)gelu32(x) * (double)wn;
                }
            }
#pragma unroll
            for (int r = 0; r < 4; ++r) {
                double v = part[r];
                v += __shfl_xor(v, 1);
                v += __shfl_xor(v, 2);
                v += __shfl_xor(v, 4);
                v += __shfl_xor(v, 8);
                if (llo == 0)
                    atomicAdd(&fl64[row0 + wr * WROWS + mt * 16 + lhi * 4 + r], v);
            }
        }
    }
}

__global__ void flbuild_kernel(const double* __restrict__ fl64,
                               const float* __restrict__ wp2m,
                               const int* __restrict__ amask,
                               float* __restrict__ fl32) {
    int m = blockIdx.x * 256 + threadIdx.x;
    fl32[m] = (amask[m] == 0) ? -1e9f : (float)(fl64[m] + (double)wp2m[1024]);
}

// --------------------------- small kernels ---------------------------------
__global__ void wp2mean_kernel(const float* __restrict__ Wp2,
                               const float* __restrict__ bp2,
                               float* __restrict__ outv) {
    __shared__ double sb[256];
    int r = blockIdx.x, tid = threadIdx.x;
    const float* src = (r < 1024) ? (Wp2 + (size_t)r * 1024) : bp2;
    double s = 0.0;
    for (int k = tid; k < 1024; k += 256) s += (double)src[k];
    sb[tid] = s; __syncthreads();
    for (int off = 128; off > 0; off >>= 1) {
        if (tid < off) sb[tid] += sb[tid + off];
        __syncthreads();
    }
    if (tid == 0) outv[r] = (float)(sb[0] * (1.0 / 1024.0));
}

__global__ void rootmean_kernel(const float* __restrict__ root, float* __restrict__ rmean,
                                unsigned short* __restrict__ rmean_bf) {
    int b = blockIdx.x;
    int h = blockIdx.y * 256 + threadIdx.x;
    const float* base = root + (size_t)b * SHC + h;
    double s = 0.0;
    for (int ss = 0; ss < SEQ; ss++) s += (double)base[(size_t)ss * HDIM];
    float v = (float)(s * (1.0 / 1024.0));
    rmean[b * HDIM + h] = v;
    rmean_bf[b * HDIM + h] = f2bf(v);
}

__global__ __launch_bounds__(256)
void ctrl_fc1(const float* __restrict__ root, const float* __restrict__ W,
              const float* __restrict__ b1, float* __restrict__ T1) {
    __shared__ double red[16][17];
    int ni = threadIdx.x & 15, kt = threadIdx.x >> 4;
    int n = blockIdx.x * 16 + ni;
    double accb[16];
#pragma unroll
    for (int bb = 0; bb < 16; ++bb) accb[bb] = 0.0;
    for (int k = kt * 64; k < kt * 64 + 64; ++k) {
        double w = (double)W[(long)k * 1024 + n];
#pragma unroll
        for (int bb = 0; bb < 16; ++bb)
            accb[bb] = fma((double)root[(long)bb * SHC + k], w, accb[bb]);
    }
    for (int bb = 0; bb < 16; ++bb) {
        red[kt][ni] = accb[bb];
        __syncthreads();
        if (kt == 0) {
            double s = 0.0;
            for (int q = 0; q < 16; ++q) s += red[q][ni];
            double x = s + (double)b1[n];
            T1[bb * 1024 + n] = (float)(0.5 * x * (1.0 + erf(x * 0.70710678118654752440)));
        }
        __syncthreads();
    }
}

__global__ void ctrl_fc2(const float* __restrict__ T1, const float* __restrict__ W2,
                         const float* __restrict__ b2, float* __restrict__ logits) {
    __shared__ double sb[256];
    int bn = blockIdx.x;
    int b = bn / 5, n = bn % 5;
    double s = 0.0;
    for (int k = threadIdx.x; k < 1024; k += 256)
        s += (double)T1[b * 1024 + k] * (double)W2[k * 5 + n];
    sb[threadIdx.x] = s; __syncthreads();
    for (int off = 128; off > 0; off >>= 1) {
        if (threadIdx.x < off) sb[threadIdx.x] += sb[threadIdx.x + off];
        __syncthreads();
    }
    if (threadIdx.x == 0) logits[b * 5 + n] = (float)(sb[0] + (double)b2[n]);
}

__global__ void sims_kernel(const float* __restrict__ logits, int* __restrict__ sims) {
    int b = threadIdx.x;
    if (b >= BATCH) return;
    float best = logits[b * 5 + 0]; int biv = 0;
    for (int i = 1; i < 5; i++) {
        float v = logits[b * 5 + i];
        if (v > best) { best = v; biv = i; }
    }
    const int opt[5] = {10, 25, 50, 75, 100};
    sims[b] = opt[biv];
}

// Per (t,b): JAX PARTITIONABLE threefry (byte-identical to rounds 5-13)
__global__ void gumbel_kernel(const float* __restrict__ fl,
                              int* __restrict__ idxj, int* __restrict__ vidx) {
    __shared__ float sv[256][3];
    __shared__ int   si[256][3];
    int blk = blockIdx.x;           // c = t*16+b
    int t = blk >> 4, b = blk & 15;
    uint32_t kk0, kk1;
    threefry(0u, 42u, 0u, (uint32_t)t, kk0, kk1);   // fold_in(key(42), t)
    int tid = threadIdx.x;
    float bv[3] = {-INFINITY, -INFINITY, -INFINITY};
    int   bi[3] = {0x7FFFFFFF, 0x7FFFFFFF, 0x7FFFFFFF};
    for (int s = tid; s < SEQ; s += 256) {
        uint32_t m = (uint32_t)(b * SEQ + s);
        uint32_t y0, y1;
        threefry(kk0, kk1, 0u, m, y0, y1);
        uint32_t bits = y0 ^ y1;
        float f = __uint_as_float((bits >> 9) | 0x3F800000u) - 1.0f;
        float u = fmaxf(1.17549435e-38f, f);
        float l1 = (float)log((double)u);
        float l2 = (float)log(-(double)l1);
        float g  = -l2;
        float val = fl[b * SEQ + s] + g;
        if (better(val, s, bv[2], bi[2])) {
            bv[2] = val; bi[2] = s;
            if (better(bv[2], bi[2], bv[1], bi[1])) {
                float tv = bv[1]; int ti = bi[1];
                bv[1] = bv[2]; bi[1] = bi[2]; bv[2] = tv; bi[2] = ti;
            }
            if (better(bv[1], bi[1], bv[0], bi[0])) {
                float tv = bv[0]; int ti = bi[0];
                bv[0] = bv[1]; bi[0] = bi[1]; bv[1] = tv; bi[1] = ti;
            }
        }
    }
    sv[tid][0] = bv[0]; sv[tid][1] = bv[1]; sv[tid][2] = bv[2];
    si[tid][0] = bi[0]; si[tid][1] = bi[1]; si[tid][2] = bi[2];
    __syncthreads();
    for (int off = 128; off > 0; off >>= 1) {
        if (tid < off) {
            float av[3] = {sv[tid][0], sv[tid][1], sv[tid][2]};
            int   ai[3] = {si[tid][0], si[tid][1], si[tid][2]};
            float cv[3] = {sv[tid + off][0], sv[tid + off][1], sv[tid + off][2]};
            int   ci[3] = {si[tid + off][0], si[tid + off][1], si[tid + off][2]};
            float rv[3]; int ri[3]; int pa = 0, pb = 0;
#pragma unroll
            for (int r = 0; r < 3; r++) {
                if (better(av[pa], ai[pa], cv[pb], ci[pb])) { rv[r] = av[pa]; ri[r] = ai[pa]; pa++; }
                else                                        { rv[r] = cv[pb]; ri[r] = ci[pb]; pb++; }
            }
            sv[tid][0] = rv[0]; sv[tid][1] = rv[1]; sv[tid][2] = rv[2];
            si[tid][0] = ri[0]; si[tid][1] = ri[1]; si[tid][2] = ri[2];
        }
        __syncthreads();
    }
    if (tid == 0) {
        idxj[0 * NCHAIN + blk] = b * SEQ + si[0][0];
        idxj[1 * NCHAIN + blk] = b * SEQ + si[0][1];
        idxj[2 * NCHAIN + blk] = b * SEQ + si[0][2];
        vidx[blk] = b;
    }
}

__global__ void meaninit_kernel(const float* __restrict__ rmean, float* __restrict__ mean_cur,
                                unsigned short* __restrict__ mc_bf) {
    int e = blockIdx.x * 256 + threadIdx.x;
    int c = e >> 10, hh = e & 1023;
    float v = rmean[(c & 15) * HDIM + hh];
    mean_cur[e] = v;
    mc_bf[e] = f2bf(v);
}

__global__ void meanupd_kernel(const float* __restrict__ NSj, const float* __restrict__ root,
                               const int* __restrict__ idx, float* __restrict__ mean_cur,
                               unsigned short* __restrict__ mc_bf) {
    int e = blockIdx.x * 256 + threadIdx.x;
    int c = e >> 10, hh = e & 1023;
    int r = idx[c];
    double m = (double)mean_cur[e] +
               ((double)NSj[e] - (double)root[(size_t)r * HDIM + hh]) * (1.0 / 1024.0);
    float v = (float)m;
    mean_cur[e] = v;
    mc_bf[e] = f2bf(v);
}

__global__ void valdot_kernel(const float* __restrict__ HV, const float* __restrict__ Wav2,
                              const float* __restrict__ bav2, float* __restrict__ w) {
    __shared__ double sb[256];
    int c = blockIdx.x, tid = threadIdx.x;
    double s = 0.0;
    for (int k = tid; k < HDIM; k += 256) s += (double)HV[(size_t)c * HDIM + k] * (double)Wav2[k];
    sb[tid] = s; __syncthreads();
    for (int off = 128; off > 0; off >>= 1) {
        if (tid < off) sb[tid] += sb[tid + off];
        __syncthreads();
    }
    if (tid == 0) {
        double v = sb[0] + (double)bav2[0];
        w[c] = (float)(1.0 / (1.0 + exp(-v)));
    }
}

__global__ void wsum_kernel(const float* __restrict__ w, const int* __restrict__ sims,
                            double* __restrict__ Wsum) {
    int b = threadIdx.x;
    if (b >= BATCH) return;
    int sb = sims[b];
    double s = 0.0;
    for (int t = 0; t < sb; t++) s += (double)w[t * BATCH + b];
    Wsum[b] = s;
}

__global__ void accinit_kernel(const float* __restrict__ root, const double* __restrict__ Wsum,
                               float* __restrict__ acc) {
    size_t e = (size_t)blockIdx.x * 256 + threadIdx.x;
    int b = (int)(e >> 20);
    acc[e] = (float)((1.0 + Wsum[b]) * (double)root[e]);
}

__global__ __launch_bounds__(256)
void corrections_atomic(const float* __restrict__ NS, const float* __restrict__ root,
                        const float* __restrict__ w, const int* __restrict__ sims,
                        const int* __restrict__ idxj, float* __restrict__ acc) {
    int blk = blockIdx.x;                // 0..4799
    int j = blk / NCHAIN, c = blk % NCHAIN;
    int b = c & 15, t = c >> 4;
    if (t >= sims[b]) return;
    float wv = w[c];
    int row = idxj[j * NCHAIN + c];
    const float* ns = NS + ((long)j * NCHAIN + c) * 1024;
    const float* rt = root + (long)row * 1024;
    float* ac = acc + (long)row * 1024;
    for (int h = threadIdx.x; h < 1024; h += 256)
        atomicAdd(&ac[h], wv * (ns[h] - rt[h]));
}

// ------------------------------- launch ------------------------------------
extern "C" void kernel_launch(void* const* d_in, const int* in_sizes, int n_in,
                              void* d_out, int out_size, void* d_ws, size_t ws_size,
                              hipStream_t stream) {
    (void)in_sizes; (void)n_in; (void)out_size; (void)ws_size;
    const float* root = (const float*)d_in[0];
    const int*   amask = (const int*)d_in[1];
    const float* Wsc1 = (const float*)d_in[2];  const float* bsc1 = (const float*)d_in[3];
    const float* Wsc2 = (const float*)d_in[4];  const float* bsc2 = (const float*)d_in[5];
    const float* Wp1  = (const float*)d_in[6];  const float* bp1  = (const float*)d_in[7];
    const float* Wp2  = (const float*)d_in[8];  const float* bp2  = (const float*)d_in[9];
    const float* Wt1  = (const float*)d_in[10]; const float* bt1  = (const float*)d_in[11];
    const float* Wt2  = (const float*)d_in[12]; const float* bt2  = (const float*)d_in[13];
    const float* Wav1 = (const float*)d_in[14]; const float* bav1 = (const float*)d_in[15];
    const float* Wav2 = (const float*)d_in[16]; const float* bav2 = (const float*)d_in[17];
    const float* Wg1  = (const float*)d_in[18]; const float* bg1  = (const float*)d_in[19];
    const float* Wg2  = (const float*)d_in[20]; const float* bg2  = (const float*)d_in[21];
    float* out = (float*)d_out;

    // ---- workspace carving (~123.6 MB; < round-10's proven 127.8 MB) ----
    char* p = (char*)d_ws;
    auto carve = [&](size_t nbytes) -> void* {
        void* r = (void*)p; p += (nbytes + 255) & ~(size_t)255; return r;
    };
    float*          mean_cur = (float*)carve((size_t)NCHAIN * HDIM * 4);
    unsigned short* H1bf     = (unsigned short*)carve((size_t)NCHAIN * HDIM * 2);
    float*          Hav      = (float*)carve((size_t)NCHAIN * HDIM * 4);
    float*          NS       = (float*)carve((size_t)3 * NCHAIN * HDIM * 4);
    unsigned short* h_bf     = (unsigned short*)mean_cur;  // step-9 alias (33.55MB<=36MB)
    unsigned short* WT3      = (unsigned short*)NS;        // policy weights: dead before NS written
    unsigned short* WTt1  = (unsigned short*)carve((size_t)1024 * 2048 * 2);
    unsigned short* WTt2  = (unsigned short*)carve((size_t)1024 * 1024 * 2);
    unsigned short* WTav1 = (unsigned short*)carve((size_t)1024 * 2048 * 2);
    unsigned short* WTg1  = (unsigned short*)carve((size_t)1024 * 2048 * 2);
    unsigned short* WTg2  = (unsigned short*)carve((size_t)1024 * 1024 * 2);
    float*  rmean  = (float*)carve(BATCH * HDIM * 4);
    float*  T1     = (float*)carve(BATCH * HDIM * 4);
    float*  logits = (float*)carve(128 * 4);
    float*  wp2m   = (float*)carve(1040 * 4);
    double* fl64   = (double*)carve((size_t)BATCH * SEQ * 8);
    float*  fl32   = (float*)carve(BATCH * SEQ * 4);
    float*  wbuf   = (float*)carve(NCHAIN * 4);
    double* Wsumd  = (double*)carve(64 * 8);
    int*    sims   = (int*)carve(64 * 4);
    int*    idxj   = (int*)carve(3 * NCHAIN * 4);
    int*    vidx   = (int*)carve(NCHAIN * 4);
    unsigned short* root_bf     = (unsigned short*)carve((size_t)BATCH * SEQ * HDIM * 2);
    unsigned short* acc_bf      = (unsigned short*)carve((size_t)BATCH * SEQ * HDIM * 2);
    unsigned short* root_lo     = acc_bf;   // policy (step 4) dead before acc_bf (step 8b)
    unsigned short* mean_cur_bf = (unsigned short*)carve((size_t)NCHAIN * HDIM * 2);
    unsigned short* rmean_bf    = (unsigned short*)carve(BATCH * HDIM * 2);

    const long NTOT8 = (long)BATCH * SEQ * HDIM / 8;
    const int  KBIG = 1 << 30, KMA = 0x7FFFFFFF;

    // 1) weight transposes (+ policy hi/lo triple-stack)
    transpose_bf16<<<dim3(2048 / 32, 1024 / 32), 256, 0, stream>>>(Wt1, WTt1, 2048, 1024);
    transpose_bf16<<<dim3(1024 / 32, 1024 / 32), 256, 0, stream>>>(Wt2, WTt2, 1024, 1024);
    transpose_bf16<<<dim3(2048 / 32, 1024 / 32), 256, 0, stream>>>(Wav1, WTav1, 2048, 1024);
    transpose_bf16<<<dim3(2048 / 32, 1024 / 32), 256, 0, stream>>>(Wg1, WTg1, 2048, 1024);
    transpose_bf16<<<dim3(1024 / 32, 1024 / 32), 256, 0, stream>>>(Wg2, WTg2, 1024, 1024);
    transpose_split3<<<dim3(32, 32), 256, 0, stream>>>(Wp1, WT3, 1024, 1024);
    // 1b) root -> bf16 hi+lo once (root_lo aliases acc_bf)
    cvt_split<<<2048, 256, 0, stream>>>(root, root_bf, root_lo, NTOT8);
    // 2) wp2 means, root mean
    wp2mean_kernel<<<1025, 256, 0, stream>>>(Wp2, bp2, wp2m);
    rootmean_kernel<<<dim3(BATCH, HDIM / 256), 256, 0, stream>>>(root, rmean, rmean_bf);
    // 3) controller (fp64) -> sims
    ctrl_fc1<<<64, 256, 0, stream>>>(root, Wsc1, bsc1, T1);
    ctrl_fc2<<<80, 256, 0, stream>>>(T1, Wsc2, bsc2, logits);
    sims_kernel<<<1, 64, 0, stream>>>(logits, sims);
    // 4) policy as pipelined K=3072 GEMM ([hi|hi|lo]) + fused fl epilogue
    hipMemsetAsync(fl64, 0, (size_t)BATCH * SEQ * 8, stream);
    gemm_bt<128, 1><<<dim3(8, 128), 512, 0, stream>>>(
        root_bf, 1024, nullptr, root_lo, 1024, nullptr, 2048, 1023,
        WT3, bp1, wp2m, fl64, nullptr, nullptr, nullptr, 1024,
        BATCH * SEQ, 1024, 3072, 0);
    flbuild_kernel<<<BATCH * SEQ / 256, 256, 0, stream>>>(fl64, wp2m, amask, fl32);
    // 5) gumbel top-3 (partitionable threefry, unchanged)
    gumbel_kernel<<<NCHAIN, 256, 0, stream>>>(fl32, idxj, vidx);
    // 6) transitions (TM=64, pipelined)
    meaninit_kernel<<<NCHAIN * HDIM / 256, 256, 0, stream>>>(rmean, mean_cur, mean_cur_bf);
    for (int j = 0; j < 3; j++) {
        gemm_bt<64, 0><<<dim3(8, 25), 512, 0, stream>>>(
            mean_cur_bf, 1024, nullptr, root_bf, 1024, idxj + j * NCHAIN, 1024, KMA,
            WTt1, bt1, nullptr, nullptr, nullptr, nullptr, H1bf, 1024,
            NCHAIN, 1024, 2048, 1);
        gemm_bt<64, 0><<<dim3(8, 25), 512, 0, stream>>>(
            H1bf, 1024, nullptr, nullptr, 0, nullptr, KBIG, KMA,
            WTt2, bt2, nullptr, nullptr, nullptr, NS + (size_t)j * NCHAIN * HDIM, nullptr,
            1024, NCHAIN, 1024, 1024, 0);
        meanupd_kernel<<<NCHAIN * HDIM / 256, 256, 0, stream>>>(
            NS + (size_t)j * NCHAIN * HDIM, root, idxj + j * NCHAIN, mean_cur, mean_cur_bf);
    }
    // 7) action value -> w -> Wsum
    gemm_bt<64, 0><<<dim3(8, 25), 512, 0, stream>>>(
        rmean_bf, 1024, vidx, mean_cur_bf, 1024, nullptr, 1024, KMA,
        WTav1, bav1, nullptr, nullptr, nullptr, Hav, nullptr, 1024,
        NCHAIN, 1024, 2048, 1);
    valdot_kernel<<<NCHAIN, 256, 0, stream>>>(Hav, Wav2, bav2, wbuf);
    wsum_kernel<<<1, 64, 0, stream>>>(wbuf, sims, Wsumd);
    // 8) acc (in d_out): init + parallel corrections + bf16 copy
    accinit_kernel<<<(BATCH * SEQ * HDIM) / 256, 256, 0, stream>>>(root, Wsumd, out);
    corrections_atomic<<<3 * NCHAIN, 256, 0, stream>>>(NS, root, wbuf, sims, idxj, out);
    cvt_split<<<2048, 256, 0, stream>>>(out, acc_bf, nullptr, NTOT8);
    // 9) aggregation (TM=128, pipelined)
    gemm_bt<128, 0><<<dim3(8, 128), 512, 0, stream>>>(
        root_bf, 1024, nullptr, acc_bf, 1024, nullptr, 1024, KMA,
        WTg1, bg1, nullptr, nullptr, nullptr, nullptr, h_bf, 1024,
        BATCH * SEQ, 1024, 2048, 1);
    gemm_bt<128, 0><<<dim3(8, 128), 512, 0, stream>>>(
        h_bf, 1024, nullptr, nullptr, 0, nullptr, KBIG, KMA,
        WTg2, bg2, nullptr, nullptr, root, out, nullptr, 1024,
        BATCH * SEQ, 1024, 1024, 0);
}